// Round 10
// baseline (294.781 us; speedup 1.0000x reference)
//
#include <hip/hip_runtime.h>
#include <math.h>

// ---- problem constants ----
#define B_   2
#define T_   2048
#define D_   1024
#define H_   16
#define DH_  64
#define DC_  1024
#define DFF_ 1656
#define DFFP_ 1664
#define MTOT 4096          // B_*T_
#define NELEM_X 4194304ull // B*T*D

typedef short s16x8 __attribute__((ext_vector_type(8)));
typedef unsigned short u16x4 __attribute__((ext_vector_type(4)));
typedef float f32x4 __attribute__((ext_vector_type(4)));
typedef float f32x16 __attribute__((ext_vector_type(16)));
typedef unsigned short bfbits;

__device__ __forceinline__ bfbits f2bf(float f) {
  unsigned int u = __builtin_bit_cast(unsigned int, f);
  u += 0x7fffu + ((u >> 16) & 1u);          // RNE
  return (bfbits)(u >> 16);
}
__device__ __forceinline__ float bf2f(bfbits b) {
  unsigned int u = ((unsigned int)b) << 16;
  return __builtin_bit_cast(float, u);
}

__device__ __forceinline__ float vexp2(float x) {   // 2^x via HW transcendental
  float r;
  asm("v_exp_f32 %0, %1" : "=v"(r) : "v"(x));
  return r;
}
__device__ __forceinline__ unsigned pkbf(float lo, float hi) { // 2xbf16 pack, RNE
  unsigned r;
  asm("v_cvt_pk_bf16_f32 %0, %1, %2" : "=v"(r) : "v"(lo), "v"(hi));
  return r;
}

__device__ __forceinline__ void gload16(const void* g, void* l) {
  __builtin_amdgcn_global_load_lds(
      (__attribute__((address_space(1))) void*)g,
      (__attribute__((address_space(3))) void*)l, 16, 0, 0);
}

// ---------- workspace offsets (bytes) ----------
constexpr size_t OFF_X1   = 0;                                  // f32 x1
constexpr size_t OFF_H    = OFF_X1 + 4ull*NELEM_X;              // bf16 h ; later h2
constexpr size_t OFF_Q    = OFF_H  + 2ull*NELEM_X;              // bf16 Q [BH][T][64] ; later ffmid
constexpr size_t OFF_K    = OFF_Q  + 2ull*NELEM_X;              // bf16 K [BH][T][64]
constexpr size_t OFF_VT   = OFF_K  + 2ull*NELEM_X;              // bf16 V^T [BH][64][T]
constexpr size_t OFF_AO   = OFF_VT + 2ull*NELEM_X;              // bf16 attn out [M][D]
constexpr size_t OFF_X2   = OFF_AO + 2ull*NELEM_X;              // f32 x2; pO(bf16) alias during attn
constexpr size_t OFF_WQKV = OFF_X2 + 4ull*NELEM_X;              // bf16 [3072][1024]
constexpr size_t OFF_WO   = OFF_WQKV + 3072ull*1024*2;          // bf16 [1024][1024]
constexpr size_t OFF_WUP  = OFF_WO   + 1024ull*1024*2;          // bf16 [1664][1024]
constexpr size_t OFF_WDN  = OFF_WUP  + 1664ull*1024*2;          // bf16 [1024][1664]
constexpr size_t OFF_BVEC = OFF_WDN  + 1024ull*1664*2;          // f32 [B][D]
constexpr size_t OFF_CBV  = OFF_BVEC + 2048ull*4;               // f32 [B]
constexpr size_t OFF_GATE = OFF_CBV  + 256;                     // f32 [M]
constexpr size_t OFF_PART = OFF_GATE + 4096ull*4;               // f32 [128][1024]
constexpr size_t OFF_POOL = OFF_PART + 128ull*1024*4;           // f32 [B][D]
constexpr size_t OFF_CMT  = OFF_POOL + 2048ull*4;               // f32 [B]
constexpr size_t OFF_PM   = OFF_CMT  + 256;                     // f32 [1856][64]
constexpr size_t OFF_PL   = OFF_PM   + 512ull*1024;             // f32 [1856][64]

// ---- attention job table: 68 jobs per bh, sorted longest-first.
// entry = qt | t0<<8 | t1<<16 | jslot<<24 (jslot=255 -> full job, direct write)
// Pieces of <=10 k-tiles; partial slots 0..57 per bh (pbase: qt<20:(qt-10)*2,
// qt<30: 20+(qt-20)*3, else 50+(qt-30)*4).
#define JB(q,a,b,s) ((unsigned)(q) | ((unsigned)(a)<<8) | ((unsigned)(b)<<16) | ((unsigned)(s)<<24))
__constant__ unsigned JOBS2[68] = {
  JB(9,0,10,255),
  JB(10,0,10,0),  JB(11,0,10,2),  JB(12,0,10,4),  JB(13,0,10,6),
  JB(14,0,10,8),  JB(15,0,10,10), JB(16,0,10,12), JB(17,0,10,14),
  JB(18,0,10,16), JB(19,0,10,18), JB(20,0,10,20), JB(21,0,10,23),
  JB(22,0,10,26), JB(23,0,10,29), JB(24,0,10,32), JB(25,0,10,35),
  JB(26,0,10,38), JB(27,0,10,41), JB(28,0,10,44), JB(29,0,10,47),
  JB(30,0,10,50), JB(31,0,10,54),
  JB(19,10,20,19), JB(20,10,20,21), JB(21,10,20,24), JB(22,10,20,27),
  JB(23,10,20,30), JB(24,10,20,33), JB(25,10,20,36), JB(26,10,20,39),
  JB(27,10,20,42), JB(28,10,20,45), JB(29,10,20,48), JB(30,10,20,51),
  JB(31,10,20,55),
  JB(29,20,30,49), JB(30,20,30,52), JB(31,20,30,56),
  JB(8,0,9,255),  JB(18,10,19,17), JB(28,20,29,46),
  JB(7,0,8,255),  JB(17,10,18,15), JB(27,20,28,43),
  JB(6,0,7,255),  JB(16,10,17,13), JB(26,20,27,40),
  JB(5,0,6,255),  JB(15,10,16,11), JB(25,20,26,37),
  JB(4,0,5,255),  JB(14,10,15,9),  JB(24,20,25,34),
  JB(3,0,4,255),  JB(13,10,14,7),  JB(23,20,24,31),
  JB(2,0,3,255),  JB(12,10,13,5),  JB(22,20,23,28),
  JB(1,0,2,255),  JB(11,10,12,3),  JB(21,20,22,25), JB(31,30,32,57),
  JB(0,0,1,255),  JB(10,10,11,1),  JB(20,20,21,22), JB(30,30,31,53),
};

// ---------- batched weight transpose: f32 [R][C] -> bf16 [Npad][Rpad], 6 jobs
__global__ __launch_bounds__(256)
void transpose_all(const float* __restrict__ wq, const float* __restrict__ wk,
                   const float* __restrict__ wv, const float* __restrict__ wo,
                   const float* __restrict__ up, const float* __restrict__ dn,
                   char* __restrict__ ws) {
  const int bid = blockIdx.x;
  const float* src;
  bfbits* dst;
  int R, C, Rpad, Npad, gw, loc;
  if (bid < 4096) {
    R = C = Rpad = Npad = 1024; gw = 32;
    const int j = bid >> 10; loc = bid & 1023;
    src = (j == 0) ? wq : (j == 1) ? wk : (j == 2) ? wv : wo;
    dst = (j < 3) ? (bfbits*)(ws + OFF_WQKV) + (size_t)j * 1024 * 1024
                  : (bfbits*)(ws + OFF_WO);
  } else if (bid < 5760) {
    R = 1024; C = DFF_; Rpad = 1024; Npad = DFFP_; gw = 32; loc = bid - 4096;
    src = up; dst = (bfbits*)(ws + OFF_WUP);
  } else {
    R = DFF_; C = 1024; Rpad = DFFP_; Npad = 1024; gw = 52; loc = bid - 5760;
    src = dn; dst = (bfbits*)(ws + OFF_WDN);
  }
  const int kb = (loc % gw) * 32, nb = (loc / gw) * 32;
  __shared__ float tile[32][33];
  const int tx = threadIdx.x & 31, ty = threadIdx.x >> 5;
  for (int i = ty; i < 32; i += 8) {
    const int k = kb + i, n = nb + tx;
    tile[i][tx] = (k < R && n < C) ? src[(size_t)k * C + n] : 0.f;
  }
  __syncthreads();
  for (int i = ty; i < 32; i += 8) {
    const int n = nb + i, k = kb + tx;
    if (n < Npad && k < Rpad) dst[(size_t)n * Rpad + k] = f2bf(tile[tx][i]);
  }
}

// ---------- fused: bvec GEMV (blocks 0..31) + cb scalar dot (block 32)
__global__ __launch_bounds__(256)
void bvec_cb_kernel(const float* __restrict__ cfa, const float* __restrict__ bw,
                    const float* __restrict__ bb, const float* __restrict__ cbw,
                    float* __restrict__ bvec, float* __restrict__ cbv) {
  const int b = blockIdx.y;
  if (blockIdx.x == 32) {
    const int tid = threadIdx.x;
    float4 a = *(const float4*)(cfa + b * 1024 + tid * 4);
    float4 w = *(const float4*)(cbw + tid * 4);
    float s = a.x * w.x + a.y * w.y + a.z * w.z + a.w * w.w;
    #pragma unroll
    for (int o = 32; o > 0; o >>= 1) s += __shfl_xor(s, o);
    __shared__ float ls[4];
    if ((tid & 63) == 0) ls[tid >> 6] = s;
    __syncthreads();
    if (tid == 0) cbv[b] = ls[0] + ls[1] + ls[2] + ls[3];
    return;
  }
  const int dl = threadIdx.x & 31, cl = threadIdx.x >> 5;
  const int d = blockIdx.x * 32 + dl;
  const float* vb = cfa + b * 1024;
  float s = 0.f;
  #pragma unroll 4
  for (int c = cl; c < 1024; c += 8)
    s += vb[c] * bw[(size_t)c * 1024 + d];
  __shared__ float red[8][32];
  red[cl][dl] = s;
  __syncthreads();
  if (threadIdx.x < 32) {
    float t = 0.f;
    #pragma unroll
    for (int i = 0; i < 8; ++i) t += red[i][threadIdx.x];
    const int dd = blockIdx.x * 32 + threadIdx.x;
    bvec[b * 1024 + dd] = t + bb[dd];
  }
}

// ---------- GEMV: out[b][d] = tanh(vec[b] @ w[.][d] + bias[d])
__global__ __launch_bounds__(256)
void gemv_t(const float* __restrict__ v, const float* __restrict__ w,
            const float* __restrict__ bias, float* __restrict__ out) {
  const int b = blockIdx.y;
  const int dl = threadIdx.x & 31, cl = threadIdx.x >> 5;
  const int d = blockIdx.x * 32 + dl;
  const float* vb = v + b * 1024;
  float s = 0.f;
  #pragma unroll 4
  for (int c = cl; c < 1024; c += 8)
    s += vb[c] * w[(size_t)c * 1024 + d];
  __shared__ float red[8][32];
  red[cl][dl] = s;
  __syncthreads();
  if (threadIdx.x < 32) {
    float t = 0.f;
    #pragma unroll
    for (int i = 0; i < 8; ++i) t += red[i][threadIdx.x];
    const int dd = blockIdx.x * 32 + threadIdx.x;
    out[b * 1024 + dd] = tanhf(t + bias[dd]);
  }
}

__device__ __forceinline__ void blockreduce3(float& a, float& b, float& c) {
  #pragma unroll
  for (int o = 32; o > 0; o >>= 1) {
    a += __shfl_xor(a, o);
    b += __shfl_xor(b, o);
    c += __shfl_xor(c, o);
  }
  __shared__ float ls[3][4];
  const int lane = threadIdx.x & 63, w = threadIdx.x >> 6;
  if (lane == 0) { ls[0][w] = a; ls[1][w] = b; ls[2][w] = c; }
  __syncthreads();
  a = ls[0][0] + ls[0][1] + ls[0][2] + ls[0][3];
  b = ls[1][0] + ls[1][1] + ls[1][2] + ls[1][3];
  c = ls[2][0] + ls[2][1] + ls[2][2] + ls[2][3];
}

// ---------- fused: x1 = x + bvec ; gate ; LN(x1) -> h (bf16)
__global__ __launch_bounds__(256)
void ln1_kernel(const float* __restrict__ x, const float* __restrict__ bvec,
                const float* __restrict__ cbv, const float* __restrict__ gw,
                const float* __restrict__ gb, const float* __restrict__ nfg,
                const float* __restrict__ nfb, float* __restrict__ x1,
                bfbits* __restrict__ h, float* __restrict__ gate_ws,
                float* __restrict__ gate_out) {
  const int m = blockIdx.x, tid = threadIdx.x, b = m >> 11;
  const size_t ro = (size_t)m * D_ + tid * 4;
  float4 xv = *(const float4*)(x + ro);
  float4 bv = *(const float4*)(bvec + b * D_ + tid * 4);
  float4 v;
  v.x = xv.x + bv.x; v.y = xv.y + bv.y; v.z = xv.z + bv.z; v.w = xv.w + bv.w;
  float4 g4 = *(const float4*)(gw + tid * 4);
  float s  = v.x + v.y + v.z + v.w;
  float s2 = v.x*v.x + v.y*v.y + v.z*v.z + v.w*v.w;
  float dg = v.x*g4.x + v.y*g4.y + v.z*g4.z + v.w*g4.w;
  blockreduce3(s, s2, dg);
  const float mean = s * (1.0f/1024.0f);
  const float var  = s2 * (1.0f/1024.0f) - mean*mean;
  const float rstd = rsqrtf(var + 1e-5f);
  if (tid == 0) {
    const float logits = dg + gb[0] + cbv[b];
    const float prob = 1.0f / (1.0f + expf(-logits));
    const float hard = prob > 0.5f ? 1.0f : 0.0f;
    const float gv = (hard - prob) + prob;
    gate_ws[m] = gv; gate_out[m] = gv;
  }
  *(float4*)(x1 + ro) = v;
  float4 gg = *(const float4*)(nfg + tid * 4);
  float4 b2 = *(const float4*)(nfb + tid * 4);
  u16x4 hv;
  hv[0] = f2bf((v.x - mean) * rstd * gg.x + b2.x);
  hv[1] = f2bf((v.y - mean) * rstd * gg.y + b2.y);
  hv[2] = f2bf((v.z - mean) * rstd * gg.z + b2.z);
  hv[3] = f2bf((v.w - mean) * rstd * gg.w + b2.w);
  *(u16x4*)(h + ro) = hv;
}

__global__ __launch_bounds__(256)
void ln2_kernel(const float* __restrict__ x2, const float* __restrict__ gptr,
                const float* __restrict__ bptr, bfbits* __restrict__ h2) {
  const int m = blockIdx.x, tid = threadIdx.x;
  const size_t ro = (size_t)m * D_ + tid * 4;
  float4 v = *(const float4*)(x2 + ro);
  float s  = v.x + v.y + v.z + v.w;
  float s2 = v.x*v.x + v.y*v.y + v.z*v.z + v.w*v.w;
  float d0 = 0.f;
  blockreduce3(s, s2, d0);
  const float mean = s * (1.0f/1024.0f);
  const float var  = s2 * (1.0f/1024.0f) - mean*mean;
  const float rstd = rsqrtf(var + 1e-5f);
  float4 gg = *(const float4*)(gptr + tid * 4);
  float4 b2 = *(const float4*)(bptr + tid * 4);
  u16x4 hv;
  hv[0] = f2bf((v.x - mean) * rstd * gg.x + b2.x);
  hv[1] = f2bf((v.y - mean) * rstd * gg.y + b2.y);
  hv[2] = f2bf((v.z - mean) * rstd * gg.z + b2.z);
  hv[3] = f2bf((v.w - mean) * rstd * gg.w + b2.w);
  *(u16x4*)(h2 + ro) = hv;
}

// ---------- GEMM: C[M][N] = A[M][K](bf16) * Bt[N][K](bf16), double-buffered LDS,
// XOR-swizzled staging (source-side) so ds_read_b128 is ~conflict-free.
// EPI 0: QKV (rope+gate, Q*(1/8)*log2e; V -> V^T)  [128,32,128]
// EPI 1: WO (x2 = x1 + C*gate)                      [64,64,64]
// EPI 2: UP (gelu(C+up_b) -> bf16, ldc=1664)        [64,64,64]
// EPI 3: DN fused final (outx = x2+cmt*gate*(C+b))  [64,64,64]
template <int EPI, int BM, int BK, int BN>
__global__ void __launch_bounds__(256, 2)
gemm_bt(const bfbits* __restrict__ A, int lda,
        const bfbits* __restrict__ Bt, int ldb, int K,
        const float* __restrict__ p0, const float* __restrict__ p1,
        const float* __restrict__ p2,
        float* __restrict__ fo0, const float* __restrict__ fo1,
        bfbits* __restrict__ bo0, bfbits* __restrict__ bo1,
        bfbits* __restrict__ bo2) {
  constexpr int MI = BM / 32;               // m-fragments per wave
  constexpr int NJ = BN / 32;               // n-fragments per wave
  constexpr int RCH = BK / 8;               // 16B chunks per row
  constexpr int NK = BK / 32;               // 32-wide k sub-steps
  __shared__ bfbits Asl[2][BM * BK];
  __shared__ bfbits Bsl[2][BN * BK];
  const int tid = threadIdx.x;
  const int lane = tid & 63, wave = tid >> 6;
  const int g = lane >> 4, l15 = lane & 15;
  const int wr = wave >> 1, wc = wave & 1;
  const int m0 = blockIdx.y * BM, n0 = blockIdx.x * BN;

  auto stage = [&](int k0, int p) {
    #pragma unroll
    for (int i = 0; i < (BM * RCH) / 256; ++i) {
      const int c = i * 256 + tid;
      const int row = c / RCH;
      const int ko = ((c % RCH) ^ (row & (RCH - 1))) * 8;
      gload16(A + (size_t)(m0 + row) * lda + (k0 + ko),
              (char*)&Asl[p][0] + c * 16);
    }
    #pragma unroll
    for (int i = 0; i < (BN * RCH) / 256; ++i) {
      const int c = i * 256 + tid;
      const int row = c / RCH;
      const int ko = ((c % RCH) ^ (row & (RCH - 1))) * 8;
      gload16(Bt + (size_t)(n0 + row) * ldb + (k0 + ko),
              (char*)&Bsl[p][0] + c * 16);
    }
  };

  f32x4 acc[MI][NJ] = {};
  stage(0, 0);
  __syncthreads();

  int t = 0;
  for (int k0 = 0; k0 < K; k0 += BK, ++t) {
    const int p = t & 1;
    if (k0 + BK < K) stage(k0 + BK, p ^ 1);
    s16x8 af[NK][MI], bfr[NK][NJ];
    #pragma unroll
    for (int kk = 0; kk < NK; ++kk) {
      #pragma unroll
      for (int i = 0; i < MI; ++i) {
        const int row = wr * (MI * 16) + i * 16 + l15;
        af[kk][i] = *(const s16x8*)&Asl[p][row * BK + (((kk * 4 + g) ^ (row & (RCH - 1))) * 8)];
      }
      #pragma unroll
      for (int i = 0; i < NJ; ++i) {
        const int row = wc * (NJ * 16) + i * 16 + l15;
        bfr[kk][i] = *(const s16x8*)&Bsl[p][row * BK + (((kk * 4 + g) ^ (row & (RCH - 1))) * 8)];
      }
    }
    #pragma unroll
    for (int kk = 0; kk < NK; ++kk)
      #pragma unroll
      for (int i = 0; i < MI; ++i)
        #pragma unroll
        for (int j = 0; j < NJ; ++j)
          acc[i][j] = __builtin_amdgcn_mfma_f32_16x16x32_bf16(af[kk][i], bfr[kk][j], acc[i][j], 0, 0, 0);
    __syncthreads();
  }

  const int b = m0 >> 11;
  const int trow0 = (m0 & 2047) + wr * (MI * 16);

  if constexpr (EPI == 0) {
    const float* gate = p0;
    const float* phase = p1;
    const int ncol0 = n0 + wc * 64;
    const int section = ncol0 >> 10;          // 0=Q 1=K 2=V
    const int hh = (ncol0 & 1023) >> 6;
    if (section == 2) {
      bfbits* vt = bo2;
      const size_t vhead = (size_t)(b * H_ + hh) * DH_ * T_;
      #pragma unroll
      for (int mi = 0; mi < MI; ++mi) {
        const int tb = trow0 + mi * 16 + g * 4;
        #pragma unroll
        for (int ni = 0; ni < NJ; ++ni) {
          const int dh = ni * 16 + l15;
          unsigned* dst32 = (unsigned*)&vt[vhead + (size_t)dh * T_ + tb];
          dst32[0] = pkbf(acc[mi][ni][0], acc[mi][ni][1]);
          dst32[1] = pkbf(acc[mi][ni][2], acc[mi][ni][3]);
        }
      }
    } else {
      const float cc = cosf(phase[hh]);
      const float ssn = sinf(phase[hh]);
      // Q carries 1/sqrt(DH) and log2(e): scores land in exp2 domain.
      const float qs = (section == 0) ? 0.125f * 1.44269504088896341f : 1.0f;
      bfbits* dst = (section == 0) ? bo0 : bo1;
      const size_t head = (size_t)(b * H_ + hh) * T_ * DH_;
      #pragma unroll
      for (int mi = 0; mi < MI; ++mi) {
        const int tb = trow0 + mi * 16 + g * 4;
        float gv[4];
        #pragma unroll
        for (int r = 0; r < 4; ++r) gv[r] = gate[(size_t)b * T_ + tb + r] * qs;
        #pragma unroll
        for (int ni = 0; ni < 2; ++ni) {
          const int dh = ni * 16 + l15;
          #pragma unroll
          for (int r = 0; r < 4; ++r) {
            const float re = acc[mi][ni][r];
            const float im = acc[mi][ni + 2][r];
            const size_t idx = head + (size_t)(tb + r) * DH_ + dh;
            dst[idx]      = f2bf((re * cc - im * ssn) * gv[r]);
            dst[idx + 32] = f2bf((re * ssn + im * cc) * gv[r]);
          }
        }
      }
    }
  } else if constexpr (EPI == 1) {
    const float* gate = p0;
    const float* x1 = fo1;
    float* x2 = fo0;
    #pragma unroll
    for (int mi = 0; mi < MI; ++mi) {
      const int m = m0 + wr * (MI * 16) + mi * 16 + g * 4;
      float gv[4];
      #pragma unroll
      for (int r = 0; r < 4; ++r) gv[r] = gate[m + r];
      #pragma unroll
      for (int ni = 0; ni < NJ; ++ni) {
        const int n = n0 + wc * (NJ * 16) + ni * 16 + l15;
        #pragma unroll
        for (int r = 0; r < 4; ++r) {
          const size_t idx = (size_t)(m + r) * D_ + n;
          x2[idx] = x1[idx] + acc[mi][ni][r] * gv[r];
        }
      }
    }
  } else if constexpr (EPI == 2) {
    const float* upb = p0;
    bfbits* outm = bo0;
    #pragma unroll
    for (int mi = 0; mi < MI; ++mi) {
      const int m = m0 + wr * (MI * 16) + mi * 16 + g * 4;
      #pragma unroll
      for (int ni = 0; ni < NJ; ++ni) {
        const int n = n0 + wc * (NJ * 16) + ni * 16 + l15;
        const float bb = upb[n < DFF_ ? n : DFF_ - 1];
        #pragma unroll
        for (int r = 0; r < 4; ++r) {
          float v = acc[mi][ni][r] + bb;
          v = 0.5f * v * (1.0f + erff(v * 0.70710678118654752f));
          outm[(size_t)(m + r) * DFFP_ + n] = f2bf(v);
        }
      }
    }
  } else {
    const float* dnb = p0;
    const float* gate = p1;
    const float* cmt = p2;
    const float* x2 = fo1;
    float* outx = fo0;
    const float cb = cmt[b];
    #pragma unroll
    for (int mi = 0; mi < MI; ++mi) {
      const int m = m0 + wr * (MI * 16) + mi * 16 + g * 4;
      float kv[4];
      #pragma unroll
      for (int r = 0; r < 4; ++r) kv[r] = cb * gate[m + r];
      #pragma unroll
      for (int ni = 0; ni < NJ; ++ni) {
        const int n = n0 + wc * (NJ * 16) + ni * 16 + l15;
        const float bb = dnb[n];
        #pragma unroll
        for (int r = 0; r < 4; ++r) {
          const size_t idx = (size_t)(m + r) * D_ + n;
          outx[idx] = x2[idx] + kv[r] * (acc[mi][ni][r] + bb);
        }
      }
    }
  }
}

// ---------- flash attention v9: uniform <=10-tile jobs + HW refill.
// 2176 blocks x 2 waves; wave owns 32 q-rows; KVBLK=64; single-buffer LDS
// (16KB -> 8 blocks/CU resident, refill queue of 128). Long jobs dispatched
// first. Partial jobs store m,l (f32) + unnormalized O^T (bf16); merged after.
__global__ void __launch_bounds__(128, 4)
attn_kernel(const bfbits* __restrict__ Qb, const bfbits* __restrict__ Kb,
            const bfbits* __restrict__ Vt, bfbits* __restrict__ AO,
            float* __restrict__ pm, float* __restrict__ pl,
            bfbits* __restrict__ pO) {
  __shared__ bfbits Kl[64 * 64];   // [k row][dh], chunk-swizzled
  __shared__ bfbits Vl[64 * 64];   // [dh row][k], chunk-swizzled
  const int pid = blockIdx.x;         // 0..2175
  const int bh = pid & 31;
  const unsigned job = JOBS2[pid >> 5];
  const int qt = job & 0xFF;
  const int t0 = (job >> 8) & 0xFF;
  const int t1 = (job >> 16) & 0xFF;
  const int js = job >> 24;           // 255 = full job
  const int qb0 = qt * 64;
  const int tid = threadIdx.x, lane = tid & 63, wq = tid >> 6;
  const int l31 = lane & 31, hi = lane >> 5;
  const int qw = qb0 + wq * 32;       // wave q base

  const bfbits* Qp = Qb + ((size_t)bh * T_ + qw) * DH_;
  const bfbits* Kp = Kb + (size_t)bh * T_ * DH_;
  const bfbits* Vp = Vt + (size_t)bh * DH_ * T_;

  // Q fragments (B-operand): lane l -> Q[qw + l31][mf*16 + hi*8 + e]
  s16x8 qf[4];
  #pragma unroll
  for (int mf = 0; mf < 4; ++mf)
    qf[mf] = *(const s16x8*)(Qp + l31 * DH_ + mf * 16 + hi * 8);

  f32x16 o0 = {}, o1 = {};            // O^T[dh][q], dh-halves 0..31 / 32..63
  float mrun = -INFINITY, lrun = 0.f;

  // staging: chunk c = i*128+tid; row=c>>3; src col chunk = (c&7)^(row&7)
  const bfbits* kg[4];
  const bfbits* vg[4];
  int cb_[4];
  #pragma unroll
  for (int i = 0; i < 4; ++i) {
    const int c = i * 128 + tid;
    const int row = c >> 3;
    const int sc = ((c & 7) ^ (row & 7)) * 8;
    kg[i] = Kp + row * DH_ + sc;
    vg[i] = Vp + (size_t)row * T_ + sc;
    cb_[i] = c * 16;
  }

  for (int t = t0; t < t1; ++t) {
    const int k0 = t << 6;
    #pragma unroll
    for (int i = 0; i < 4; ++i) {
      gload16(kg[i] + (size_t)k0 * DH_, (char*)&Kl[0] + cb_[i]);
      gload16(vg[i] + k0,               (char*)&Vl[0] + cb_[i]);
    }
    __syncthreads();                  // drains vmcnt -> tiles ready
    // ---- QK^T: S^T[64k][32q], two 32x32 halves ----
    f32x16 s0 = {}, s1 = {};
    __builtin_amdgcn_s_setprio(1);
    #pragma unroll
    for (int mf = 0; mf < 4; ++mf) {
      const int ch = ((mf * 2 + hi) ^ (l31 & 7)) * 8;
      const s16x8 ka  = *(const s16x8*)&Kl[l31 * 64 + ch];
      const s16x8 kb2 = *(const s16x8*)&Kl[(32 + l31) * 64 + ch];
      s0 = __builtin_amdgcn_mfma_f32_32x32x16_bf16(ka,  qf[mf], s0, 0, 0, 0);
      s1 = __builtin_amdgcn_mfma_f32_32x32x16_bf16(kb2, qf[mf], s1, 0, 0, 0);
    }
    __builtin_amdgcn_s_setprio(0);
    // ---- causal mask (only the diagonal tile t == qt) ----
    if (t == qt) {
      const int qd = wq * 32 + l31;       // q - k0
      #pragma unroll
      for (int r = 0; r < 16; ++r) {
        const int krow = (r & 3) + 8 * (r >> 2) + 4 * hi;
        if (krow > qd)      s0[r] = -1e9f;
        if (krow + 32 > qd) s1[r] = -1e9f;
      }
    }
    // ---- online softmax (exp2 domain), in-lane tree + 1 shfl ----
    float red[8];
    #pragma unroll
    for (int i = 0; i < 8; ++i)
      red[i] = fmaxf(fmaxf(s0[i], s0[i + 8]), fmaxf(s1[i], s1[i + 8]));
    #pragma unroll
    for (int i = 0; i < 4; ++i) red[i] = fmaxf(red[i], red[i + 4]);
    float mx = fmaxf(fmaxf(red[0], red[1]), fmaxf(red[2], red[3]));
    mx = fmaxf(mx, __shfl_xor(mx, 32));
    const bool need = __any(mx > mrun + 8.f) != 0;   // defer-max
    const float mnew = need ? fmaxf(mrun, mx) : mrun;
    s0 = s0 - mnew;
    s1 = s1 - mnew;
    #pragma unroll
    for (int i = 0; i < 16; ++i) { s0[i] = vexp2(s0[i]); s1[i] = vexp2(s1[i]); }
    float sr[8];
    #pragma unroll
    for (int i = 0; i < 8; ++i)
      sr[i] = (s0[i] + s0[i + 8]) + (s1[i] + s1[i + 8]);
    #pragma unroll
    for (int i = 0; i < 4; ++i) sr[i] += sr[i + 4];
    float sum = (sr[0] + sr[1]) + (sr[2] + sr[3]);
    sum += __shfl_xor(sum, 32);
    if (need) {
      const float alpha = vexp2(mrun - mnew);
      mrun = mnew;
      lrun = lrun * alpha + sum;
      o0 *= alpha;
      o1 *= alpha;
    } else {
      lrun += sum;
    }
    // ---- pack P subtiles + PV (O^T += V^T * P^T) ----
    #pragma unroll
    for (int mf = 0; mf < 4; ++mf) {
      const f32x16& s = (mf < 2) ? s0 : s1;
      const int r0 = (mf & 1) * 8;
      const unsigned A0 = pkbf(s[r0 + 0], s[r0 + 1]);
      const unsigned A1 = pkbf(s[r0 + 2], s[r0 + 3]);
      const unsigned B0 = pkbf(s[r0 + 4], s[r0 + 5]);
      const unsigned B1 = pkbf(s[r0 + 6], s[r0 + 7]);
      const unsigned x0 = (unsigned)__shfl_xor((int)(hi ? A0 : B0), 32);
      const unsigned x1 = (unsigned)__shfl_xor((int)(hi ? A1 : B1), 32);
      uint4 wv;
      wv.x = hi ? x0 : A0;
      wv.y = hi ? x1 : A1;
      wv.z = hi ? B0 : x0;
      wv.w = hi ? B1 : x1;
      const s16x8 pf = __builtin_bit_cast(s16x8, wv);
      const int ch = ((mf * 2 + hi) ^ (l31 & 7)) * 8;
      const s16x8 v0 = *(const s16x8*)&Vl[l31 * 64 + ch];
      const s16x8 v1 = *(const s16x8*)&Vl[(32 + l31) * 64 + ch];
      __builtin_amdgcn_s_setprio(1);
      o0 = __builtin_amdgcn_mfma_f32_32x32x16_bf16(v0, pf, o0, 0, 0, 0);
      o1 = __builtin_amdgcn_mfma_f32_32x32x16_bf16(v1, pf, o1, 0, 0, 0);
      __builtin_amdgcn_s_setprio(0);
    }
    __syncthreads();                  // all reads done before next overwrite
  }

  if (js == 255) {
    // ---- direct epilogue: reg r -> dh = (r&3)+8*(r>>2)+4*hi, col q = l31 ----
    const float inv = 1.0f / lrun;
    const int q = qw + l31;
    bfbits* dst = AO + ((size_t)(bh >> 4) * T_ + q) * D_ + (bh & 15) * DH_;
    #pragma unroll
    for (int rp = 0; rp < 8; ++rp) {
      const int dh = ((2 * rp) & 3) + 8 * (rp >> 1) + 4 * hi;
      *(unsigned*)(dst + dh)      = pkbf(o0[2 * rp] * inv, o0[2 * rp + 1] * inv);
      *(unsigned*)(dst + 32 + dh) = pkbf(o1[2 * rp] * inv, o1[2 * rp + 1] * inv);
    }
  } else {
    // ---- partial epilogue: store m, l (f32) and unnormalized O^T (bf16) ----
    const int jid = bh * 58 + js;
    const int qloc = wq * 32 + l31;
    pm[jid * 64 + qloc] = mrun;
    pl[jid * 64 + qloc] = lrun;
    bfbits* po = pO + (size_t)jid * 4096;
    #pragma unroll
    for (int r = 0; r < 16; ++r) {
      const int dh = (r & 3) + 8 * (r >> 2) + 4 * hi;
      po[dh * 64 + qloc]        = f2bf(o0[r]);
      po[(dh + 32) * 64 + qloc] = f2bf(o1[r]);
    }
  }
}

// ---------- merge split-K attention partials (qt 10..31, 2-4 parts) ----------
__global__ void __launch_bounds__(64)
attn_merge(const float* __restrict__ pm, const float* __restrict__ pl,
           const bfbits* __restrict__ pO, bfbits* __restrict__ AO) {
  __shared__ float lds[64][65];
  const int u = blockIdx.x;             // 0..703
  const int qt = 10 + (u >> 5), bh = u & 31;
  const int q = threadIdx.x;            // 0..63
  const int P = (qt + 10) / 10;         // ceil((qt+1)/10), 2..4
  const int pbase = (qt < 20) ? (qt - 10) * 2
                  : (qt < 30) ? 20 + (qt - 20) * 3
                              : 50 + (qt - 30) * 4;
  const int jb = bh * 58 + pbase;
  float mv[4], ev[4];
  float m = -INFINITY;
  for (int p = 0; p < P; ++p) {
    mv[p] = pm[(jb + p) * 64 + q];
    m = fmaxf(m, mv[p]);
  }
  float l = 0.f;
  for (int p = 0; p < P; ++p) {
    ev[p] = vexp2(mv[p] - m);
    l += pl[(jb + p) * 64 + q] * ev[p];
  }
  const float inv = 1.0f / l;
  for (int dh = 0; dh < 64; ++dh) {
    float acc = 0.f;
    for (int p = 0; p < P; ++p)
      acc += bf2f(pO[(size_t)(jb + p) * 4096 + dh * 64 + q]) * ev[p];
    lds[dh][q] = acc * inv;
  }
  __syncthreads();
  const int b = bh >> 4, hh = bh & 15;
  bfbits* dst = AO + ((size_t)b * T_ + qt * 64) * D_ + hh * DH_ + q; // thread=dh col
  for (int qq = 0; qq < 64; ++qq)
    dst[(size_t)qq * D_] = f2bf(lds[q][qq]);
}

// ---------- pooling / commit ----------
__global__ __launch_bounds__(256)
void pool_part(const float* __restrict__ x2, float* __restrict__ part) {
  const int s = blockIdx.x, b = blockIdx.y, tid = threadIdx.x;
  const float* base = x2 + ((size_t)b * T_ + s * 32) * D_ + tid * 4;
  float ax = 0, ay = 0, az = 0, aw = 0;
  #pragma unroll 4
  for (int t = 0; t < 32; ++t) {
    float4 v = *(const float4*)(base + (size_t)t * D_);
    ax += v.x; ay += v.y; az += v.z; aw += v.w;
  }
  float4 ov; ov.x = ax; ov.y = ay; ov.z = az; ov.w = aw;
  *(float4*)(part + (size_t)(b * 64 + s) * D_ + tid * 4) = ov;
}

// pool_fin + commit fused: block b computes pool row AND commit[b]
__global__ __launch_bounds__(256)
void pool_fin_commit(const float* __restrict__ part, const float* __restrict__ cw,
                     const float* __restrict__ cb0, float* __restrict__ pool,
                     float* __restrict__ cmt, float* __restrict__ out_cmt) {
  const int b = blockIdx.x, tid = threadIdx.x;
  const int d0 = tid * 4;
  float ax = 0, ay = 0, az = 0, aw = 0;
  #pragma unroll 8
  for (int i = 0; i < 64; ++i) {
    float4 v = *(const float4*)(part + (size_t)(b * 64 + i) * D_ + d0);
    ax += v.x; ay += v.y; az += v.z; aw += v.w;
  }
  ax *= (1.0f / 2048.0f); ay *= (1.0f / 2048.0f);
  az *= (1.0f / 2048.0f); aw *= (1.0f / 2048.0f);
  float4 ov; ov.x = ax; ov.y = ay; ov.z = az; ov.w = aw;
  *(float4*)(pool + b * 1024 + d0) = ov;
  float4 w = *(const float4*)(cw + d0);
  float s = ax * w.x + ay * w.y + az * w.z + aw * w.w;
  #pragma unroll
  for (int o = 32; o > 0; o >>= 1) s += __shfl_xor(s, o);
  __shared__ float ls[4];
  if ((tid & 63) == 0) ls[tid >> 6] = s;
  __syncthreads();
  if (tid == 0) {
    const float t = ls[0] + ls[1] + ls[2] + ls[3] + cb0[0];
    const float v = 1.0f / (1.0f + expf(-t));
    cmt[b] = v; out_cmt[b] = v;
  }
}

// ---------------- host launcher ----------------
extern "C" void kernel_launch(void* const* d_in, const int* in_sizes, int n_in,
                              void* d_out, int out_size, void* d_ws, size_t ws_size,
                              hipStream_t stream) {
  (void)in_sizes; (void)n_in; (void)out_size; (void)ws_size;
  const float* x       = (const float*)d_in[0];
  const float* cfa     = (const float*)d_in[1];
  const float* gate_w  = (const float*)d_in[3];
  const float* gate_b  = (const float*)d_in[4];
  const float* cb_w    = (const float*)d_in[5];
  const float* nf_g    = (const float*)d_in[6];
  const float* nf_b    = (const float*)d_in[7];
  const float* wq      = (const float*)d_in[8];
  const float* wk      = (const float*)d_in[9];
  const float* wv      = (const float*)d_in[10];
  const float* wo      = (const float*)d_in[11];
  const float* phase   = (const float*)d_in[12];
  const float* nb_g    = (const float*)d_in[13];
  const float* nb_b    = (const float*)d_in[14];
  const float* up_w    = (const float*)d_in[15];
  const float* up_b    = (const float*)d_in[16];
  const float* dn_w    = (const float*)d_in[17];
  const float* dn_b    = (const float*)d_in[18];
  const float* cmt_w   = (const float*)d_in[19];
  const float* cmt_b   = (const float*)d_in[20];
  const float* cproj_w = (const float*)d_in[21];
  const float* cproj_b = (const float*)d_in[22];
  const float* bcast_w = (const float*)d_in[23];
  const float* bcast_b = (const float*)d_in[24];

  char* ws = (char*)d_ws;
  float*  x1     = (float*)(ws + OFF_X1);
  bfbits* h      = (bfbits*)(ws + OFF_H);
  bfbits* h2     = (bfbits*)(ws + OFF_H);     // alias: h dead after QKV
  bfbits* qb     = (bfbits*)(ws + OFF_Q);
  bfbits* kb     = (bfbits*)(ws + OFF_K);
  bfbits* vt     = (bfbits*)(ws + OFF_VT);
  bfbits* ffmid  = (bfbits*)(ws + OFF_Q);     // alias: Q/K dead after attention
  bfbits* ao     = (bfbits*)(ws + OFF_AO);
  float*  x2     = (float*)(ws + OFF_X2);
  bfbits* pO     = (bfbits*)(ws + OFF_X2);    // alias: x2 written after merge
  bfbits* wqkv_t = (bfbits*)(ws + OFF_WQKV);
  bfbits* wo_t   = (bfbits*)(ws + OFF_WO);
  bfbits* wup_t  = (bfbits*)(ws + OFF_WUP);
  bfbits* wdn_t  = (bfbits*)(ws + OFF_WDN);
  float*  bvec   = (float*)(ws + OFF_BVEC);
  float*  cbv    = (float*)(ws + OFF_CBV);
  float*  gate   = (float*)(ws + OFF_GATE);
  float*  part   = (float*)(ws + OFF_PART);
  float*  pool   = (float*)(ws + OFF_POOL);
  float*  cmt    = (float*)(ws + OFF_CMT);
  float*  pm     = (float*)(ws + OFF_PM);
  float*  pl     = (float*)(ws + OFF_PL);

  float* outx   = (float*)d_out;
  float* outc   = outx + NELEM_X;          // center [B][DC]
  float* outg   = outc + B_ * DC_;         // gate [B][T]
  float* outcmt = outg + B_ * T_;          // commit [B]

  // weight prep (B^T bf16), all 6 in one launch
  transpose_all<<<7424, 256, 0, stream>>>(wq, wk, wv, wo, up_w, dn_w, ws);

  bvec_cb_kernel<<<dim3(33, B_), 256, 0, stream>>>(cfa, bcast_w, bcast_b, cb_w,
                                                   bvec, cbv);

  ln1_kernel<<<MTOT, 256, 0, stream>>>(x, bvec, cbv, gate_w, gate_b, nf_g, nf_b,
                                       x1, h, gate, outg);

  gemm_bt<0, 128, 32, 128><<<dim3(24, 32), 256, 0, stream>>>(
      h, 1024, wqkv_t, 1024, 1024, gate, phase, nullptr,
      nullptr, nullptr, qb, kb, vt);

  attn_kernel<<<2176, 128, 0, stream>>>(qb, kb, vt, ao, pm, pl, pO);
  attn_merge<<<704, 64, 0, stream>>>(pm, pl, pO, ao);

  gemm_bt<1, 64, 64, 64><<<dim3(16, 64), 256, 0, stream>>>(
      ao, 1024, wo_t, 1024, 1024, gate, nullptr, nullptr,
      x2, x1, nullptr, nullptr, nullptr);

  ln2_kernel<<<MTOT, 256, 0, stream>>>(x2, nb_g, nb_b, h2);

  // pooled stats only need x2 -> run before FF so DN can fuse the final add
  pool_part<<<dim3(64, B_), 256, 0, stream>>>(x2, part);
  pool_fin_commit<<<B_, 256, 0, stream>>>(part, cmt_w, cmt_b, pool, cmt, outcmt);
  gemv_t<<<dim3(32, B_), 256, 0, stream>>>(pool, cproj_w, cproj_b, outc);

  gemm_bt<2, 64, 64, 64><<<dim3(26, 64), 256, 0, stream>>>(
      h2, 1024, wup_t, 1024, 1024, up_b, nullptr, nullptr,
      nullptr, nullptr, ffmid, nullptr, nullptr);

  gemm_bt<3, 64, 64, 64><<<dim3(16, 64), 256, 0, stream>>>(
      ffmid, DFFP_, wdn_t, DFFP_, DFFP_, dn_b, gate, cmt,
      outx, x2, nullptr, nullptr, nullptr);
}

// Round 11
// 233.208 us; speedup vs baseline: 1.2640x; 1.2640x over previous
//
#include <hip/hip_runtime.h>
#include <math.h>

// ---- problem constants ----
#define B_   2
#define T_   2048
#define D_   1024
#define H_   16
#define DH_  64
#define DC_  1024
#define DFF_ 1656
#define DFFP_ 1664
#define MTOT 4096          // B_*T_
#define NELEM_X 4194304ull // B*T*D

typedef short s16x8 __attribute__((ext_vector_type(8)));
typedef unsigned short u16x4 __attribute__((ext_vector_type(4)));
typedef unsigned short u16x8 __attribute__((ext_vector_type(8)));
typedef float f32x4 __attribute__((ext_vector_type(4)));
typedef float f32x16 __attribute__((ext_vector_type(16)));
typedef unsigned short bfbits;

__device__ __forceinline__ bfbits f2bf(float f) {
  unsigned int u = __builtin_bit_cast(unsigned int, f);
  u += 0x7fffu + ((u >> 16) & 1u);          // RNE
  return (bfbits)(u >> 16);
}
__device__ __forceinline__ float bf2f(bfbits b) {
  unsigned int u = ((unsigned int)b) << 16;
  return __builtin_bit_cast(float, u);
}

__device__ __forceinline__ float vexp2(float x) {   // 2^x via HW transcendental
  float r;
  asm("v_exp_f32 %0, %1" : "=v"(r) : "v"(x));
  return r;
}
__device__ __forceinline__ unsigned pkbf(float lo, float hi) { // 2xbf16 pack, RNE
  unsigned r;
  asm("v_cvt_pk_bf16_f32 %0, %1, %2" : "=v"(r) : "v"(lo), "v"(hi));
  return r;
}

__device__ __forceinline__ void gload16(const void* g, void* l) {
  __builtin_amdgcn_global_load_lds(
      (__attribute__((address_space(1))) void*)g,
      (__attribute__((address_space(3))) void*)l, 16, 0, 0);
}

// ---------- workspace offsets (bytes) ----------
constexpr size_t OFF_X1   = 0;                                  // f32 x1
constexpr size_t OFF_H    = OFF_X1 + 4ull*NELEM_X;              // bf16 h ; later h2
constexpr size_t OFF_Q    = OFF_H  + 2ull*NELEM_X;              // bf16 Q [BH][T][64] ; later ffmid
constexpr size_t OFF_K    = OFF_Q  + 2ull*NELEM_X;              // bf16 K [BH][T][64]
constexpr size_t OFF_VT   = OFF_K  + 2ull*NELEM_X;              // bf16 V^T [BH][64][T]
constexpr size_t OFF_AO   = OFF_VT + 2ull*NELEM_X;              // bf16 attn out [M][D]
constexpr size_t OFF_X2   = OFF_AO + 2ull*NELEM_X;              // f32 x2; pO(bf16) alias during attn
constexpr size_t OFF_WQKV = OFF_X2 + 4ull*NELEM_X;              // bf16 [3072][1024]
constexpr size_t OFF_WO   = OFF_WQKV + 3072ull*1024*2;          // bf16 [1024][1024]
constexpr size_t OFF_WUP  = OFF_WO   + 1024ull*1024*2;          // bf16 [1664][1024]
constexpr size_t OFF_WDN  = OFF_WUP  + 1664ull*1024*2;          // bf16 [1024][1664]
constexpr size_t OFF_BVEC = OFF_WDN  + 1024ull*1664*2;          // f32 [B][D]
constexpr size_t OFF_CBV  = OFF_BVEC + 2048ull*4;               // f32 [B]
constexpr size_t OFF_GATE = OFF_CBV  + 256;                     // f32 [M]
constexpr size_t OFF_PART = OFF_GATE + 4096ull*4;               // f32 [128][1024]
constexpr size_t OFF_POOL = OFF_PART + 128ull*1024*4;           // f32 [B][D]
constexpr size_t OFF_CMT  = OFF_POOL + 2048ull*4;               // f32 [B]
constexpr size_t OFF_PM   = OFF_CMT  + 256;                     // f32 [1856][64]
constexpr size_t OFF_PL   = OFF_PM   + 512ull*1024;             // f32 [1856][64]

// ---- attention job table: 68 jobs per bh, sorted longest-first.
// entry = qt | t0<<8 | t1<<16 | jslot<<24 (jslot=255 -> full job, direct write)
// Pieces of <=10 k-tiles; partial slots 0..57 per bh (pbase: qt<20:(qt-10)*2,
// qt<30: 20+(qt-20)*3, else 50+(qt-30)*4).
#define JB(q,a,b,s) ((unsigned)(q) | ((unsigned)(a)<<8) | ((unsigned)(b)<<16) | ((unsigned)(s)<<24))
__constant__ unsigned JOBS2[68] = {
  JB(9,0,10,255),
  JB(10,0,10,0),  JB(11,0,10,2),  JB(12,0,10,4),  JB(13,0,10,6),
  JB(14,0,10,8),  JB(15,0,10,10), JB(16,0,10,12), JB(17,0,10,14),
  JB(18,0,10,16), JB(19,0,10,18), JB(20,0,10,20), JB(21,0,10,23),
  JB(22,0,10,26), JB(23,0,10,29), JB(24,0,10,32), JB(25,0,10,35),
  JB(26,0,10,38), JB(27,0,10,41), JB(28,0,10,44), JB(29,0,10,47),
  JB(30,0,10,50), JB(31,0,10,54),
  JB(19,10,20,19), JB(20,10,20,21), JB(21,10,20,24), JB(22,10,20,27),
  JB(23,10,20,30), JB(24,10,20,33), JB(25,10,20,36), JB(26,10,20,39),
  JB(27,10,20,42), JB(28,10,20,45), JB(29,10,20,48), JB(30,10,20,51),
  JB(31,10,20,55),
  JB(29,20,30,49), JB(30,20,30,52), JB(31,20,30,56),
  JB(8,0,9,255),  JB(18,10,19,17), JB(28,20,29,46),
  JB(7,0,8,255),  JB(17,10,18,15), JB(27,20,28,43),
  JB(6,0,7,255),  JB(16,10,17,13), JB(26,20,27,40),
  JB(5,0,6,255),  JB(15,10,16,11), JB(25,20,26,37),
  JB(4,0,5,255),  JB(14,10,15,9),  JB(24,20,25,34),
  JB(3,0,4,255),  JB(13,10,14,7),  JB(23,20,24,31),
  JB(2,0,3,255),  JB(12,10,13,5),  JB(22,20,23,28),
  JB(1,0,2,255),  JB(11,10,12,3),  JB(21,20,22,25), JB(31,30,32,57),
  JB(0,0,1,255),  JB(10,10,11,1),  JB(20,20,21,22), JB(30,30,31,53),
};

// ---------- batched weight transpose: f32 [R][C] -> bf16 [Npad][Rpad], 6 jobs
__global__ __launch_bounds__(256)
void transpose_all(const float* __restrict__ wq, const float* __restrict__ wk,
                   const float* __restrict__ wv, const float* __restrict__ wo,
                   const float* __restrict__ up, const float* __restrict__ dn,
                   char* __restrict__ ws) {
  const int bid = blockIdx.x;
  const float* src;
  bfbits* dst;
  int R, C, Rpad, Npad, gw, loc;
  if (bid < 4096) {
    R = C = Rpad = Npad = 1024; gw = 32;
    const int j = bid >> 10; loc = bid & 1023;
    src = (j == 0) ? wq : (j == 1) ? wk : (j == 2) ? wv : wo;
    dst = (j < 3) ? (bfbits*)(ws + OFF_WQKV) + (size_t)j * 1024 * 1024
                  : (bfbits*)(ws + OFF_WO);
  } else if (bid < 5760) {
    R = 1024; C = DFF_; Rpad = 1024; Npad = DFFP_; gw = 32; loc = bid - 4096;
    src = up; dst = (bfbits*)(ws + OFF_WUP);
  } else {
    R = DFF_; C = 1024; Rpad = DFFP_; Npad = 1024; gw = 52; loc = bid - 5760;
    src = dn; dst = (bfbits*)(ws + OFF_WDN);
  }
  const int kb = (loc % gw) * 32, nb = (loc / gw) * 32;
  __shared__ float tile[32][33];
  const int tx = threadIdx.x & 31, ty = threadIdx.x >> 5;
  for (int i = ty; i < 32; i += 8) {
    const int k = kb + i, n = nb + tx;
    tile[i][tx] = (k < R && n < C) ? src[(size_t)k * C + n] : 0.f;
  }
  __syncthreads();
  for (int i = ty; i < 32; i += 8) {
    const int n = nb + i, k = kb + tx;
    if (n < Npad && k < Rpad) dst[(size_t)n * Rpad + k] = f2bf(tile[tx][i]);
  }
}

// ---------- fused: bvec GEMV (blocks 0..31) + cb scalar dot (block 32)
__global__ __launch_bounds__(256)
void bvec_cb_kernel(const float* __restrict__ cfa, const float* __restrict__ bw,
                    const float* __restrict__ bb, const float* __restrict__ cbw,
                    float* __restrict__ bvec, float* __restrict__ cbv) {
  const int b = blockIdx.y;
  if (blockIdx.x == 32) {
    const int tid = threadIdx.x;
    float4 a = *(const float4*)(cfa + b * 1024 + tid * 4);
    float4 w = *(const float4*)(cbw + tid * 4);
    float s = a.x * w.x + a.y * w.y + a.z * w.z + a.w * w.w;
    #pragma unroll
    for (int o = 32; o > 0; o >>= 1) s += __shfl_xor(s, o);
    __shared__ float ls[4];
    if ((tid & 63) == 0) ls[tid >> 6] = s;
    __syncthreads();
    if (tid == 0) cbv[b] = ls[0] + ls[1] + ls[2] + ls[3];
    return;
  }
  const int dl = threadIdx.x & 31, cl = threadIdx.x >> 5;
  const int d = blockIdx.x * 32 + dl;
  const float* vb = cfa + b * 1024;
  float s = 0.f;
  #pragma unroll 4
  for (int c = cl; c < 1024; c += 8)
    s += vb[c] * bw[(size_t)c * 1024 + d];
  __shared__ float red[8][32];
  red[cl][dl] = s;
  __syncthreads();
  if (threadIdx.x < 32) {
    float t = 0.f;
    #pragma unroll
    for (int i = 0; i < 8; ++i) t += red[i][threadIdx.x];
    const int dd = blockIdx.x * 32 + threadIdx.x;
    bvec[b * 1024 + dd] = t + bb[dd];
  }
}

// ---------- GEMV: out[b][d] = tanh(vec[b] @ w[.][d] + bias[d])
__global__ __launch_bounds__(256)
void gemv_t(const float* __restrict__ v, const float* __restrict__ w,
            const float* __restrict__ bias, float* __restrict__ out) {
  const int b = blockIdx.y;
  const int dl = threadIdx.x & 31, cl = threadIdx.x >> 5;
  const int d = blockIdx.x * 32 + dl;
  const float* vb = v + b * 1024;
  float s = 0.f;
  #pragma unroll 4
  for (int c = cl; c < 1024; c += 8)
    s += vb[c] * w[(size_t)c * 1024 + d];
  __shared__ float red[8][32];
  red[cl][dl] = s;
  __syncthreads();
  if (threadIdx.x < 32) {
    float t = 0.f;
    #pragma unroll
    for (int i = 0; i < 8; ++i) t += red[i][threadIdx.x];
    const int dd = blockIdx.x * 32 + threadIdx.x;
    out[b * 1024 + dd] = tanhf(t + bias[dd]);
  }
}

__device__ __forceinline__ void blockreduce3(float& a, float& b, float& c) {
  #pragma unroll
  for (int o = 32; o > 0; o >>= 1) {
    a += __shfl_xor(a, o);
    b += __shfl_xor(b, o);
    c += __shfl_xor(c, o);
  }
  __shared__ float ls[3][4];
  const int lane = threadIdx.x & 63, w = threadIdx.x >> 6;
  if (lane == 0) { ls[0][w] = a; ls[1][w] = b; ls[2][w] = c; }
  __syncthreads();
  a = ls[0][0] + ls[0][1] + ls[0][2] + ls[0][3];
  b = ls[1][0] + ls[1][1] + ls[1][2] + ls[1][3];
  c = ls[2][0] + ls[2][1] + ls[2][2] + ls[2][3];
}

// ---------- fused: x1 = x + bvec ; gate ; LN(x1) -> h (bf16)
__global__ __launch_bounds__(256)
void ln1_kernel(const float* __restrict__ x, const float* __restrict__ bvec,
                const float* __restrict__ cbv, const float* __restrict__ gw,
                const float* __restrict__ gb, const float* __restrict__ nfg,
                const float* __restrict__ nfb, float* __restrict__ x1,
                bfbits* __restrict__ h, float* __restrict__ gate_ws,
                float* __restrict__ gate_out) {
  const int m = blockIdx.x, tid = threadIdx.x, b = m >> 11;
  const size_t ro = (size_t)m * D_ + tid * 4;
  float4 xv = *(const float4*)(x + ro);
  float4 bv = *(const float4*)(bvec + b * D_ + tid * 4);
  float4 v;
  v.x = xv.x + bv.x; v.y = xv.y + bv.y; v.z = xv.z + bv.z; v.w = xv.w + bv.w;
  float4 g4 = *(const float4*)(gw + tid * 4);
  float s  = v.x + v.y + v.z + v.w;
  float s2 = v.x*v.x + v.y*v.y + v.z*v.z + v.w*v.w;
  float dg = v.x*g4.x + v.y*g4.y + v.z*g4.z + v.w*g4.w;
  blockreduce3(s, s2, dg);
  const float mean = s * (1.0f/1024.0f);
  const float var  = s2 * (1.0f/1024.0f) - mean*mean;
  const float rstd = rsqrtf(var + 1e-5f);
  if (tid == 0) {
    const float logits = dg + gb[0] + cbv[b];
    const float prob = 1.0f / (1.0f + expf(-logits));
    const float hard = prob > 0.5f ? 1.0f : 0.0f;
    const float gv = (hard - prob) + prob;
    gate_ws[m] = gv; gate_out[m] = gv;
  }
  *(float4*)(x1 + ro) = v;
  float4 gg = *(const float4*)(nfg + tid * 4);
  float4 b2 = *(const float4*)(nfb + tid * 4);
  u16x4 hv;
  hv[0] = f2bf((v.x - mean) * rstd * gg.x + b2.x);
  hv[1] = f2bf((v.y - mean) * rstd * gg.y + b2.y);
  hv[2] = f2bf((v.z - mean) * rstd * gg.z + b2.z);
  hv[3] = f2bf((v.w - mean) * rstd * gg.w + b2.w);
  *(u16x4*)(h + ro) = hv;
}

__global__ __launch_bounds__(256)
void ln2_kernel(const float* __restrict__ x2, const float* __restrict__ gptr,
                const float* __restrict__ bptr, bfbits* __restrict__ h2) {
  const int m = blockIdx.x, tid = threadIdx.x;
  const size_t ro = (size_t)m * D_ + tid * 4;
  float4 v = *(const float4*)(x2 + ro);
  float s  = v.x + v.y + v.z + v.w;
  float s2 = v.x*v.x + v.y*v.y + v.z*v.z + v.w*v.w;
  float d0 = 0.f;
  blockreduce3(s, s2, d0);
  const float mean = s * (1.0f/1024.0f);
  const float var  = s2 * (1.0f/1024.0f) - mean*mean;
  const float rstd = rsqrtf(var + 1e-5f);
  float4 gg = *(const float4*)(gptr + tid * 4);
  float4 b2 = *(const float4*)(bptr + tid * 4);
  u16x4 hv;
  hv[0] = f2bf((v.x - mean) * rstd * gg.x + b2.x);
  hv[1] = f2bf((v.y - mean) * rstd * gg.y + b2.y);
  hv[2] = f2bf((v.z - mean) * rstd * gg.z + b2.z);
  hv[3] = f2bf((v.w - mean) * rstd * gg.w + b2.w);
  *(u16x4*)(h2 + ro) = hv;
}

// ---------- GEMM: C[M][N] = A[M][K](bf16) * Bt[N][K](bf16), double-buffered LDS,
// XOR-swizzled staging (source-side) so ds_read_b128 is ~conflict-free.
// EPI 0: QKV (rope+gate, Q*(1/8)*log2e; V -> V^T)  [128,32,128]
// EPI 1: WO (x2 = x1 + C*gate)                      [64,64,64]
// EPI 2: UP (gelu(C+up_b) -> bf16, ldc=1664)        [64,64,64]
// EPI 3: DN fused final (outx = x2+cmt*gate*(C+b))  [64,64,64]
template <int EPI, int BM, int BK, int BN>
__global__ void __launch_bounds__(256, 2)
gemm_bt(const bfbits* __restrict__ A, int lda,
        const bfbits* __restrict__ Bt, int ldb, int K,
        const float* __restrict__ p0, const float* __restrict__ p1,
        const float* __restrict__ p2,
        float* __restrict__ fo0, const float* __restrict__ fo1,
        bfbits* __restrict__ bo0, bfbits* __restrict__ bo1,
        bfbits* __restrict__ bo2) {
  constexpr int MI = BM / 32;               // m-fragments per wave
  constexpr int NJ = BN / 32;               // n-fragments per wave
  constexpr int RCH = BK / 8;               // 16B chunks per row
  constexpr int NK = BK / 32;               // 32-wide k sub-steps
  __shared__ bfbits Asl[2][BM * BK];
  __shared__ bfbits Bsl[2][BN * BK];
  const int tid = threadIdx.x;
  const int lane = tid & 63, wave = tid >> 6;
  const int g = lane >> 4, l15 = lane & 15;
  const int wr = wave >> 1, wc = wave & 1;
  const int m0 = blockIdx.y * BM, n0 = blockIdx.x * BN;

  auto stage = [&](int k0, int p) {
    #pragma unroll
    for (int i = 0; i < (BM * RCH) / 256; ++i) {
      const int c = i * 256 + tid;
      const int row = c / RCH;
      const int ko = ((c % RCH) ^ (row & (RCH - 1))) * 8;
      gload16(A + (size_t)(m0 + row) * lda + (k0 + ko),
              (char*)&Asl[p][0] + c * 16);
    }
    #pragma unroll
    for (int i = 0; i < (BN * RCH) / 256; ++i) {
      const int c = i * 256 + tid;
      const int row = c / RCH;
      const int ko = ((c % RCH) ^ (row & (RCH - 1))) * 8;
      gload16(Bt + (size_t)(n0 + row) * ldb + (k0 + ko),
              (char*)&Bsl[p][0] + c * 16);
    }
  };

  f32x4 acc[MI][NJ] = {};
  stage(0, 0);
  __syncthreads();

  int t = 0;
  for (int k0 = 0; k0 < K; k0 += BK, ++t) {
    const int p = t & 1;
    if (k0 + BK < K) stage(k0 + BK, p ^ 1);
    s16x8 af[NK][MI], bfr[NK][NJ];
    #pragma unroll
    for (int kk = 0; kk < NK; ++kk) {
      #pragma unroll
      for (int i = 0; i < MI; ++i) {
        const int row = wr * (MI * 16) + i * 16 + l15;
        af[kk][i] = *(const s16x8*)&Asl[p][row * BK + (((kk * 4 + g) ^ (row & (RCH - 1))) * 8)];
      }
      #pragma unroll
      for (int i = 0; i < NJ; ++i) {
        const int row = wc * (NJ * 16) + i * 16 + l15;
        bfr[kk][i] = *(const s16x8*)&Bsl[p][row * BK + (((kk * 4 + g) ^ (row & (RCH - 1))) * 8)];
      }
    }
    #pragma unroll
    for (int kk = 0; kk < NK; ++kk)
      #pragma unroll
      for (int i = 0; i < MI; ++i)
        #pragma unroll
        for (int j = 0; j < NJ; ++j)
          acc[i][j] = __builtin_amdgcn_mfma_f32_16x16x32_bf16(af[kk][i], bfr[kk][j], acc[i][j], 0, 0, 0);
    __syncthreads();
  }

  const int b = m0 >> 11;
  const int trow0 = (m0 & 2047) + wr * (MI * 16);

  if constexpr (EPI == 0) {
    const float* gate = p0;
    const float* phase = p1;
    const int ncol0 = n0 + wc * 64;
    const int section = ncol0 >> 10;          // 0=Q 1=K 2=V
    const int hh = (ncol0 & 1023) >> 6;
    if (section == 2) {
      bfbits* vt = bo2;
      const size_t vhead = (size_t)(b * H_ + hh) * DH_ * T_;
      #pragma unroll
      for (int mi = 0; mi < MI; ++mi) {
        const int tb = trow0 + mi * 16 + g * 4;
        #pragma unroll
        for (int ni = 0; ni < NJ; ++ni) {
          const int dh = ni * 16 + l15;
          unsigned* dst32 = (unsigned*)&vt[vhead + (size_t)dh * T_ + tb];
          dst32[0] = pkbf(acc[mi][ni][0], acc[mi][ni][1]);
          dst32[1] = pkbf(acc[mi][ni][2], acc[mi][ni][3]);
        }
      }
    } else {
      const float cc = cosf(phase[hh]);
      const float ssn = sinf(phase[hh]);
      // Q carries 1/sqrt(DH) and log2(e): scores land in exp2 domain.
      const float qs = (section == 0) ? 0.125f * 1.44269504088896341f : 1.0f;
      bfbits* dst = (section == 0) ? bo0 : bo1;
      const size_t head = (size_t)(b * H_ + hh) * T_ * DH_;
      #pragma unroll
      for (int mi = 0; mi < MI; ++mi) {
        const int tb = trow0 + mi * 16 + g * 4;
        float gv[4];
        #pragma unroll
        for (int r = 0; r < 4; ++r) gv[r] = gate[(size_t)b * T_ + tb + r] * qs;
        #pragma unroll
        for (int ni = 0; ni < 2; ++ni) {
          const int dh = ni * 16 + l15;
          #pragma unroll
          for (int r = 0; r < 4; ++r) {
            const float re = acc[mi][ni][r];
            const float im = acc[mi][ni + 2][r];
            const size_t idx = head + (size_t)(tb + r) * DH_ + dh;
            dst[idx]      = f2bf((re * cc - im * ssn) * gv[r]);
            dst[idx + 32] = f2bf((re * ssn + im * cc) * gv[r]);
          }
        }
      }
    }
  } else if constexpr (EPI == 1) {
    const float* gate = p0;
    const float* x1 = fo1;
    float* x2 = fo0;
    #pragma unroll
    for (int mi = 0; mi < MI; ++mi) {
      const int m = m0 + wr * (MI * 16) + mi * 16 + g * 4;
      float gv[4];
      #pragma unroll
      for (int r = 0; r < 4; ++r) gv[r] = gate[m + r];
      #pragma unroll
      for (int ni = 0; ni < NJ; ++ni) {
        const int n = n0 + wc * (NJ * 16) + ni * 16 + l15;
        #pragma unroll
        for (int r = 0; r < 4; ++r) {
          const size_t idx = (size_t)(m + r) * D_ + n;
          x2[idx] = x1[idx] + acc[mi][ni][r] * gv[r];
        }
      }
    }
  } else if constexpr (EPI == 2) {
    const float* upb = p0;
    bfbits* outm = bo0;
    #pragma unroll
    for (int mi = 0; mi < MI; ++mi) {
      const int m = m0 + wr * (MI * 16) + mi * 16 + g * 4;
      #pragma unroll
      for (int ni = 0; ni < NJ; ++ni) {
        const int n = n0 + wc * (NJ * 16) + ni * 16 + l15;
        const float bb = upb[n < DFF_ ? n : DFF_ - 1];
        #pragma unroll
        for (int r = 0; r < 4; ++r) {
          float v = acc[mi][ni][r] + bb;
          v = 0.5f * v * (1.0f + erff(v * 0.70710678118654752f));
          outm[(size_t)(m + r) * DFFP_ + n] = f2bf(v);
        }
      }
    }
  } else {
    const float* dnb = p0;
    const float* gate = p1;
    const float* cmt = p2;
    const float* x2 = fo1;
    float* outx = fo0;
    const float cb = cmt[b];
    #pragma unroll
    for (int mi = 0; mi < MI; ++mi) {
      const int m = m0 + wr * (MI * 16) + mi * 16 + g * 4;
      float kv[4];
      #pragma unroll
      for (int r = 0; r < 4; ++r) kv[r] = cb * gate[m + r];
      #pragma unroll
      for (int ni = 0; ni < NJ; ++ni) {
        const int n = n0 + wc * (NJ * 16) + ni * 16 + l15;
        const float bb = dnb[n];
        #pragma unroll
        for (int r = 0; r < 4; ++r) {
          const size_t idx = (size_t)(m + r) * D_ + n;
          outx[idx] = x2[idx] + kv[r] * (acc[mi][ni][r] + bb);
        }
      }
    }
  }
}

// ---------- flash attention v9b: uniform <=10-tile jobs + HW refill.
// 2176 blocks x 2 waves; wave owns 32 q-rows; KVBLK=64; single-buffer LDS
// (16KB -> 8 blocks/CU resident + refill queue). Long jobs dispatched first.
// Partial jobs store m,l (f32) + unnormalized O^T as bf16 in q-major layout
// pO[jid][q*64+dh] (contiguous per q-row -> vectorizable merge).
__global__ void __launch_bounds__(128, 4)
attn_kernel(const bfbits* __restrict__ Qb, const bfbits* __restrict__ Kb,
            const bfbits* __restrict__ Vt, bfbits* __restrict__ AO,
            float* __restrict__ pm, float* __restrict__ pl,
            bfbits* __restrict__ pO) {
  __shared__ bfbits Kl[64 * 64];   // [k row][dh], chunk-swizzled
  __shared__ bfbits Vl[64 * 64];   // [dh row][k], chunk-swizzled
  const int pid = blockIdx.x;         // 0..2175
  const int bh = pid & 31;
  const unsigned job = JOBS2[pid >> 5];
  const int qt = job & 0xFF;
  const int t0 = (job >> 8) & 0xFF;
  const int t1 = (job >> 16) & 0xFF;
  const int js = job >> 24;           // 255 = full job
  const int qb0 = qt * 64;
  const int tid = threadIdx.x, lane = tid & 63, wq = tid >> 6;
  const int l31 = lane & 31, hi = lane >> 5;
  const int qw = qb0 + wq * 32;       // wave q base

  const bfbits* Qp = Qb + ((size_t)bh * T_ + qw) * DH_;
  const bfbits* Kp = Kb + (size_t)bh * T_ * DH_;
  const bfbits* Vp = Vt + (size_t)bh * DH_ * T_;

  // Q fragments (B-operand): lane l -> Q[qw + l31][mf*16 + hi*8 + e]
  s16x8 qf[4];
  #pragma unroll
  for (int mf = 0; mf < 4; ++mf)
    qf[mf] = *(const s16x8*)(Qp + l31 * DH_ + mf * 16 + hi * 8);

  f32x16 o0 = {}, o1 = {};            // O^T[dh][q], dh-halves 0..31 / 32..63
  float mrun = -INFINITY, lrun = 0.f;

  // staging: chunk c = i*128+tid; row=c>>3; src col chunk = (c&7)^(row&7)
  const bfbits* kg[4];
  const bfbits* vg[4];
  int cb_[4];
  #pragma unroll
  for (int i = 0; i < 4; ++i) {
    const int c = i * 128 + tid;
    const int row = c >> 3;
    const int sc = ((c & 7) ^ (row & 7)) * 8;
    kg[i] = Kp + row * DH_ + sc;
    vg[i] = Vp + (size_t)row * T_ + sc;
    cb_[i] = c * 16;
  }

  for (int t = t0; t < t1; ++t) {
    const int k0 = t << 6;
    #pragma unroll
    for (int i = 0; i < 4; ++i) {
      gload16(kg[i] + (size_t)k0 * DH_, (char*)&Kl[0] + cb_[i]);
      gload16(vg[i] + k0,               (char*)&Vl[0] + cb_[i]);
    }
    __syncthreads();                  // drains vmcnt -> tiles ready
    // ---- QK^T: S^T[64k][32q], two 32x32 halves ----
    f32x16 s0 = {}, s1 = {};
    __builtin_amdgcn_s_setprio(1);
    #pragma unroll
    for (int mf = 0; mf < 4; ++mf) {
      const int ch = ((mf * 2 + hi) ^ (l31 & 7)) * 8;
      const s16x8 ka  = *(const s16x8*)&Kl[l31 * 64 + ch];
      const s16x8 kb2 = *(const s16x8*)&Kl[(32 + l31) * 64 + ch];
      s0 = __builtin_amdgcn_mfma_f32_32x32x16_bf16(ka,  qf[mf], s0, 0, 0, 0);
      s1 = __builtin_amdgcn_mfma_f32_32x32x16_bf16(kb2, qf[mf], s1, 0, 0, 0);
    }
    __builtin_amdgcn_s_setprio(0);
    // ---- causal mask (only the diagonal tile t == qt) ----
    if (t == qt) {
      const int qd = wq * 32 + l31;       // q - k0
      #pragma unroll
      for (int r = 0; r < 16; ++r) {
        const int krow = (r & 3) + 8 * (r >> 2) + 4 * hi;
        if (krow > qd)      s0[r] = -1e9f;
        if (krow + 32 > qd) s1[r] = -1e9f;
      }
    }
    // ---- online softmax (exp2 domain), in-lane tree + 1 shfl ----
    float red[8];
    #pragma unroll
    for (int i = 0; i < 8; ++i)
      red[i] = fmaxf(fmaxf(s0[i], s0[i + 8]), fmaxf(s1[i], s1[i + 8]));
    #pragma unroll
    for (int i = 0; i < 4; ++i) red[i] = fmaxf(red[i], red[i + 4]);
    float mx = fmaxf(fmaxf(red[0], red[1]), fmaxf(red[2], red[3]));
    mx = fmaxf(mx, __shfl_xor(mx, 32));
    const bool need = __any(mx > mrun + 8.f) != 0;   // defer-max
    const float mnew = need ? fmaxf(mrun, mx) : mrun;
    s0 = s0 - mnew;
    s1 = s1 - mnew;
    #pragma unroll
    for (int i = 0; i < 16; ++i) { s0[i] = vexp2(s0[i]); s1[i] = vexp2(s1[i]); }
    float sr[8];
    #pragma unroll
    for (int i = 0; i < 8; ++i)
      sr[i] = (s0[i] + s0[i + 8]) + (s1[i] + s1[i + 8]);
    #pragma unroll
    for (int i = 0; i < 4; ++i) sr[i] += sr[i + 4];
    float sum = (sr[0] + sr[1]) + (sr[2] + sr[3]);
    sum += __shfl_xor(sum, 32);
    if (need) {
      const float alpha = vexp2(mrun - mnew);
      mrun = mnew;
      lrun = lrun * alpha + sum;
      o0 *= alpha;
      o1 *= alpha;
    } else {
      lrun += sum;
    }
    // ---- pack P subtiles + PV (O^T += V^T * P^T) ----
    #pragma unroll
    for (int mf = 0; mf < 4; ++mf) {
      const f32x16& s = (mf < 2) ? s0 : s1;
      const int r0 = (mf & 1) * 8;
      const unsigned A0 = pkbf(s[r0 + 0], s[r0 + 1]);
      const unsigned A1 = pkbf(s[r0 + 2], s[r0 + 3]);
      const unsigned B0 = pkbf(s[r0 + 4], s[r0 + 5]);
      const unsigned B1 = pkbf(s[r0 + 6], s[r0 + 7]);
      const unsigned x0 = (unsigned)__shfl_xor((int)(hi ? A0 : B0), 32);
      const unsigned x1 = (unsigned)__shfl_xor((int)(hi ? A1 : B1), 32);
      uint4 wv;
      wv.x = hi ? x0 : A0;
      wv.y = hi ? x1 : A1;
      wv.z = hi ? B0 : x0;
      wv.w = hi ? B1 : x1;
      const s16x8 pf = __builtin_bit_cast(s16x8, wv);
      const int ch = ((mf * 2 + hi) ^ (l31 & 7)) * 8;
      const s16x8 v0 = *(const s16x8*)&Vl[l31 * 64 + ch];
      const s16x8 v1 = *(const s16x8*)&Vl[(32 + l31) * 64 + ch];
      __builtin_amdgcn_s_setprio(1);
      o0 = __builtin_amdgcn_mfma_f32_32x32x16_bf16(v0, pf, o0, 0, 0, 0);
      o1 = __builtin_amdgcn_mfma_f32_32x32x16_bf16(v1, pf, o1, 0, 0, 0);
      __builtin_amdgcn_s_setprio(0);
    }
    __syncthreads();                  // all reads done before next overwrite
  }

  if (js == 255) {
    // ---- direct epilogue: reg r -> dh = (r&3)+8*(r>>2)+4*hi, col q = l31 ----
    const float inv = 1.0f / lrun;
    const int q = qw + l31;
    bfbits* dst = AO + ((size_t)(bh >> 4) * T_ + q) * D_ + (bh & 15) * DH_;
    #pragma unroll
    for (int rp = 0; rp < 8; ++rp) {
      const int dh = ((2 * rp) & 3) + 8 * (rp >> 1) + 4 * hi;
      *(unsigned*)(dst + dh)      = pkbf(o0[2 * rp] * inv, o0[2 * rp + 1] * inv);
      *(unsigned*)(dst + 32 + dh) = pkbf(o1[2 * rp] * inv, o1[2 * rp + 1] * inv);
    }
  } else {
    // ---- partial epilogue: m,l (f32); unnormalized O^T bf16, q-major row ----
    const int jid = bh * 58 + js;
    const int qloc = wq * 32 + l31;
    pm[jid * 64 + qloc] = mrun;
    pl[jid * 64 + qloc] = lrun;
    bfbits* po = pO + (size_t)jid * 4096 + qloc * 64;
    #pragma unroll
    for (int rp = 0; rp < 8; ++rp) {
      const int dh = ((2 * rp) & 3) + 8 * (rp >> 1) + 4 * hi;
      *(unsigned*)(po + dh)      = pkbf(o0[2 * rp], o0[2 * rp + 1]);
      *(unsigned*)(po + 32 + dh) = pkbf(o1[2 * rp], o1[2 * rp + 1]);
    }
  }
}

// ---------- merge split-K attention partials (qt 10..31, 2-4 parts) ----------
// 256 threads: thread t handles q=t>>2, dh0=(t&3)*16 -> 16 contiguous elements.
__global__ void __launch_bounds__(256)
attn_merge(const float* __restrict__ pm, const float* __restrict__ pl,
           const bfbits* __restrict__ pO, bfbits* __restrict__ AO) {
  __shared__ float evs[4][64];
  __shared__ float invs[64];
  const int u = blockIdx.x;             // 0..703
  const int qt = 10 + (u >> 5), bh = u & 31;
  const int tid = threadIdx.x;
  const int P = (qt + 10) / 10;         // ceil((qt+1)/10), 2..4
  const int pbase = (qt < 20) ? (qt - 10) * 2
                  : (qt < 30) ? 20 + (qt - 20) * 3
                              : 50 + (qt - 30) * 4;
  const int jb = bh * 58 + pbase;
  if (tid < 64) {
    const int q = tid;
    float mv[4];
    float m = -INFINITY;
    for (int p = 0; p < P; ++p) {
      mv[p] = pm[(jb + p) * 64 + q];
      m = fmaxf(m, mv[p]);
    }
    float l = 0.f;
    for (int p = 0; p < P; ++p) {
      const float e = vexp2(mv[p] - m);
      evs[p][q] = e;
      l += pl[(jb + p) * 64 + q] * e;
    }
    invs[q] = 1.0f / l;
  }
  __syncthreads();
  const int q = tid >> 2, dh0 = (tid & 3) * 16;
  float acc[16] = {};
  for (int p = 0; p < P; ++p) {
    const float e = evs[p][q];
    const bfbits* src = pO + (size_t)(jb + p) * 4096 + q * 64 + dh0;
    const u16x8 a = *(const u16x8*)src;
    const u16x8 b2 = *(const u16x8*)(src + 8);
    #pragma unroll
    for (int i = 0; i < 8; ++i) {
      acc[i]     += bf2f(a[i]) * e;
      acc[8 + i] += bf2f(b2[i]) * e;
    }
  }
  const float inv = invs[q];
  uint4 w0, w1;
  w0.x = pkbf(acc[0] * inv,  acc[1] * inv);
  w0.y = pkbf(acc[2] * inv,  acc[3] * inv);
  w0.z = pkbf(acc[4] * inv,  acc[5] * inv);
  w0.w = pkbf(acc[6] * inv,  acc[7] * inv);
  w1.x = pkbf(acc[8] * inv,  acc[9] * inv);
  w1.y = pkbf(acc[10] * inv, acc[11] * inv);
  w1.z = pkbf(acc[12] * inv, acc[13] * inv);
  w1.w = pkbf(acc[14] * inv, acc[15] * inv);
  const int b = bh >> 4, hh = bh & 15;
  bfbits* dst = AO + ((size_t)b * T_ + qt * 64 + q) * D_ + hh * DH_ + dh0;
  *(uint4*)dst = w0;
  *(uint4*)(dst + 8) = w1;
}

// ---------- pooling / commit ----------
__global__ __launch_bounds__(256)
void pool_part(const float* __restrict__ x2, float* __restrict__ part) {
  const int s = blockIdx.x, b = blockIdx.y, tid = threadIdx.x;
  const float* base = x2 + ((size_t)b * T_ + s * 32) * D_ + tid * 4;
  float ax = 0, ay = 0, az = 0, aw = 0;
  #pragma unroll 4
  for (int t = 0; t < 32; ++t) {
    float4 v = *(const float4*)(base + (size_t)t * D_);
    ax += v.x; ay += v.y; az += v.z; aw += v.w;
  }
  float4 ov; ov.x = ax; ov.y = ay; ov.z = az; ov.w = aw;
  *(float4*)(part + (size_t)(b * 64 + s) * D_ + tid * 4) = ov;
}

// pool_fin + commit fused: block b computes pool row AND commit[b]
__global__ __launch_bounds__(256)
void pool_fin_commit(const float* __restrict__ part, const float* __restrict__ cw,
                     const float* __restrict__ cb0, float* __restrict__ pool,
                     float* __restrict__ cmt, float* __restrict__ out_cmt) {
  const int b = blockIdx.x, tid = threadIdx.x;
  const int d0 = tid * 4;
  float ax = 0, ay = 0, az = 0, aw = 0;
  #pragma unroll 8
  for (int i = 0; i < 64; ++i) {
    float4 v = *(const float4*)(part + (size_t)(b * 64 + i) * D_ + d0);
    ax += v.x; ay += v.y; az += v.z; aw += v.w;
  }
  ax *= (1.0f / 2048.0f); ay *= (1.0f / 2048.0f);
  az *= (1.0f / 2048.0f); aw *= (1.0f / 2048.0f);
  float4 ov; ov.x = ax; ov.y = ay; ov.z = az; ov.w = aw;
  *(float4*)(pool + b * 1024 + d0) = ov;
  float4 w = *(const float4*)(cw + d0);
  float s = ax * w.x + ay * w.y + az * w.z + aw * w.w;
  #pragma unroll
  for (int o = 32; o > 0; o >>= 1) s += __shfl_xor(s, o);
  __shared__ float ls[4];
  if ((tid & 63) == 0) ls[tid >> 6] = s;
  __syncthreads();
  if (tid == 0) {
    const float t = ls[0] + ls[1] + ls[2] + ls[3] + cb0[0];
    const float v = 1.0f / (1.0f + expf(-t));
    cmt[b] = v; out_cmt[b] = v;
  }
}

// ---------------- host launcher ----------------
extern "C" void kernel_launch(void* const* d_in, const int* in_sizes, int n_in,
                              void* d_out, int out_size, void* d_ws, size_t ws_size,
                              hipStream_t stream) {
  (void)in_sizes; (void)n_in; (void)out_size; (void)ws_size;
  const float* x       = (const float*)d_in[0];
  const float* cfa     = (const float*)d_in[1];
  const float* gate_w  = (const float*)d_in[3];
  const float* gate_b  = (const float*)d_in[4];
  const float* cb_w    = (const float*)d_in[5];
  const float* nf_g    = (const float*)d_in[6];
  const float* nf_b    = (const float*)d_in[7];
  const float* wq      = (const float*)d_in[8];
  const float* wk      = (const float*)d_in[9];
  const float* wv      = (const float*)d_in[10];
  const float* wo      = (const float*)d_in[11];
  const float* phase   = (const float*)d_in[12];
  const float* nb_g    = (const float*)d_in[13];
  const float* nb_b    = (const float*)d_in[14];
  const float* up_w    = (const float*)d_in[15];
  const float* up_b    = (const float*)d_in[16];
  const float* dn_w    = (const float*)d_in[17];
  const float* dn_b    = (const float*)d_in[18];
  const float* cmt_w   = (const float*)d_in[19];
  const float* cmt_b   = (const float*)d_in[20];
  const float* cproj_w = (const float*)d_in[21];
  const float* cproj_b = (const float*)d_in[22];
  const float* bcast_w = (const float*)d_in[23];
  const float* bcast_b = (const float*)d_in[24];

  char* ws = (char*)d_ws;
  float*  x1     = (float*)(ws + OFF_X1);
  bfbits* h      = (bfbits*)(ws + OFF_H);
  bfbits* h2     = (bfbits*)(ws + OFF_H);     // alias: h dead after QKV
  bfbits* qb     = (bfbits*)(ws + OFF_Q);
  bfbits* kb     = (bfbits*)(ws + OFF_K);
  bfbits* vt     = (bfbits*)(ws + OFF_VT);
  bfbits* ffmid  = (bfbits*)(ws + OFF_Q);     // alias: Q/K dead after attention
  bfbits* ao     = (bfbits*)(ws + OFF_AO);
  float*  x2     = (float*)(ws + OFF_X2);
  bfbits* pO     = (bfbits*)(ws + OFF_X2);    // alias: x2 written after merge
  bfbits* wqkv_t = (bfbits*)(ws + OFF_WQKV);
  bfbits* wo_t   = (bfbits*)(ws + OFF_WO);
  bfbits* wup_t  = (bfbits*)(ws + OFF_WUP);
  bfbits* wdn_t  = (bfbits*)(ws + OFF_WDN);
  float*  bvec   = (float*)(ws + OFF_BVEC);
  float*  cbv    = (float*)(ws + OFF_CBV);
  float*  gate   = (float*)(ws + OFF_GATE);
  float*  part   = (float*)(ws + OFF_PART);
  float*  pool   = (float*)(ws + OFF_POOL);
  float*  cmt    = (float*)(ws + OFF_CMT);
  float*  pm     = (float*)(ws + OFF_PM);
  float*  pl     = (float*)(ws + OFF_PL);

  float* outx   = (float*)d_out;
  float* outc   = outx + NELEM_X;          // center [B][DC]
  float* outg   = outc + B_ * DC_;         // gate [B][T]
  float* outcmt = outg + B_ * T_;          // commit [B]

  // weight prep (B^T bf16), all 6 in one launch
  transpose_all<<<7424, 256, 0, stream>>>(wq, wk, wv, wo, up_w, dn_w, ws);

  bvec_cb_kernel<<<dim3(33, B_), 256, 0, stream>>>(cfa, bcast_w, bcast_b, cb_w,
                                                   bvec, cbv);

  ln1_kernel<<<MTOT, 256, 0, stream>>>(x, bvec, cbv, gate_w, gate_b, nf_g, nf_b,
                                       x1, h, gate, outg);

  gemm_bt<0, 128, 32, 128><<<dim3(24, 32), 256, 0, stream>>>(
      h, 1024, wqkv_t, 1024, 1024, gate, phase, nullptr,
      nullptr, nullptr, qb, kb, vt);

  attn_kernel<<<2176, 128, 0, stream>>>(qb, kb, vt, ao, pm, pl, pO);
  attn_merge<<<704, 256, 0, stream>>>(pm, pl, pO, ao);

  gemm_bt<1, 64, 64, 64><<<dim3(16, 64), 256, 0, stream>>>(
      ao, 1024, wo_t, 1024, 1024, gate, nullptr, nullptr,
      x2, x1, nullptr, nullptr, nullptr);

  ln2_kernel<<<MTOT, 256, 0, stream>>>(x2, nb_g, nb_b, h2);

  // pooled stats only need x2 -> run before FF so DN can fuse the final add
  pool_part<<<dim3(64, B_), 256, 0, stream>>>(x2, part);
  pool_fin_commit<<<B_, 256, 0, stream>>>(part, cmt_w, cmt_b, pool, cmt, outcmt);
  gemv_t<<<dim3(32, B_), 256, 0, stream>>>(pool, cproj_w, cproj_b, outc);

  gemm_bt<2, 64, 64, 64><<<dim3(26, 64), 256, 0, stream>>>(
      h2, 1024, wup_t, 1024, 1024, up_b, nullptr, nullptr,
      nullptr, nullptr, ffmid, nullptr, nullptr);

  gemm_bt<3, 64, 64, 64><<<dim3(16, 64), 256, 0, stream>>>(
      ffmid, DFFP_, wdn_t, DFFP_, DFFP_, dn_b, gate, cmt,
      outx, x2, nullptr, nullptr, nullptr);
}

// Round 12
// 216.857 us; speedup vs baseline: 1.3593x; 1.0754x over previous
//
#include <hip/hip_runtime.h>
#include <math.h>

// ---- problem constants ----
#define B_   2
#define T_   2048
#define D_   1024
#define H_   16
#define DH_  64
#define DC_  1024
#define DFF_ 1656
#define DFFP_ 1664
#define MTOT 4096          // B_*T_
#define NELEM_X 4194304ull // B*T*D

typedef short s16x8 __attribute__((ext_vector_type(8)));
typedef unsigned short u16x4 __attribute__((ext_vector_type(4)));
typedef unsigned short u16x8 __attribute__((ext_vector_type(8)));
typedef float f32x4 __attribute__((ext_vector_type(4)));
typedef float f32x16 __attribute__((ext_vector_type(16)));
typedef unsigned short bfbits;

__device__ __forceinline__ bfbits f2bf(float f) {
  unsigned int u = __builtin_bit_cast(unsigned int, f);
  u += 0x7fffu + ((u >> 16) & 1u);          // RNE
  return (bfbits)(u >> 16);
}
__device__ __forceinline__ float bf2f(bfbits b) {
  unsigned int u = ((unsigned int)b) << 16;
  return __builtin_bit_cast(float, u);
}

__device__ __forceinline__ float vexp2(float x) {   // 2^x via HW transcendental
  float r;
  asm("v_exp_f32 %0, %1" : "=v"(r) : "v"(x));
  return r;
}
__device__ __forceinline__ unsigned pkbf(float lo, float hi) { // 2xbf16 pack, RNE
  unsigned r;
  asm("v_cvt_pk_bf16_f32 %0, %1, %2" : "=v"(r) : "v"(lo), "v"(hi));
  return r;
}

__device__ __forceinline__ void gload16(const void* g, void* l) {
  __builtin_amdgcn_global_load_lds(
      (__attribute__((address_space(1))) void*)g,
      (__attribute__((address_space(3))) void*)l, 16, 0, 0);
}

// ---------- workspace offsets (bytes) ----------
constexpr size_t OFF_X1   = 0;                                  // f32 x1
constexpr size_t OFF_H    = OFF_X1 + 4ull*NELEM_X;              // bf16 h ; later h2
constexpr size_t OFF_Q    = OFF_H  + 2ull*NELEM_X;              // bf16 Q [BH][T][64] ; later ffmid
constexpr size_t OFF_K    = OFF_Q  + 2ull*NELEM_X;              // bf16 K [BH][T][64]
constexpr size_t OFF_VT   = OFF_K  + 2ull*NELEM_X;              // bf16 V^T [BH][64][T]
constexpr size_t OFF_AO   = OFF_VT + 2ull*NELEM_X;              // bf16 attn out [M][D]
constexpr size_t OFF_X2   = OFF_AO + 2ull*NELEM_X;              // f32 x2; pO(bf16) alias during attn
constexpr size_t OFF_WQKV = OFF_X2 + 4ull*NELEM_X;              // bf16 [3072][1024]
constexpr size_t OFF_WO   = OFF_WQKV + 3072ull*1024*2;          // bf16 [1024][1024]
constexpr size_t OFF_WUP  = OFF_WO   + 1024ull*1024*2;          // bf16 [1664][1024]
constexpr size_t OFF_WDN  = OFF_WUP  + 1664ull*1024*2;          // bf16 [1024][1664]
constexpr size_t OFF_BVEC = OFF_WDN  + 1024ull*1664*2;          // f32 [B][D]
constexpr size_t OFF_CBV  = OFF_BVEC + 2048ull*4;               // f32 [B]
constexpr size_t OFF_GATE = OFF_CBV  + 256;                     // f32 [M]
constexpr size_t OFF_PART = OFF_GATE + 4096ull*4;               // f32 [128][1024]
constexpr size_t OFF_POOL = OFF_PART + 128ull*1024*4;           // f32 [B][D]
constexpr size_t OFF_CMT  = OFF_POOL + 2048ull*4;               // f32 [B]
constexpr size_t OFF_PM   = OFF_CMT  + 256;                     // f32 [1856][64]
constexpr size_t OFF_PL   = OFF_PM   + 512ull*1024;             // f32 [1856][64]

// ---- attention job table: 68 jobs per bh, sorted longest-first.
// entry = qt | t0<<8 | t1<<16 | jslot<<24 (jslot=255 -> full job, direct write)
// Pieces of <=10 k-tiles; partial slots 0..57 per bh (pbase: qt<20:(qt-10)*2,
// qt<30: 20+(qt-20)*3, else 50+(qt-30)*4).
#define JB(q,a,b,s) ((unsigned)(q) | ((unsigned)(a)<<8) | ((unsigned)(b)<<16) | ((unsigned)(s)<<24))
__constant__ unsigned JOBS2[68] = {
  JB(9,0,10,255),
  JB(10,0,10,0),  JB(11,0,10,2),  JB(12,0,10,4),  JB(13,0,10,6),
  JB(14,0,10,8),  JB(15,0,10,10), JB(16,0,10,12), JB(17,0,10,14),
  JB(18,0,10,16), JB(19,0,10,18), JB(20,0,10,20), JB(21,0,10,23),
  JB(22,0,10,26), JB(23,0,10,29), JB(24,0,10,32), JB(25,0,10,35),
  JB(26,0,10,38), JB(27,0,10,41), JB(28,0,10,44), JB(29,0,10,47),
  JB(30,0,10,50), JB(31,0,10,54),
  JB(19,10,20,19), JB(20,10,20,21), JB(21,10,20,24), JB(22,10,20,27),
  JB(23,10,20,30), JB(24,10,20,33), JB(25,10,20,36), JB(26,10,20,39),
  JB(27,10,20,42), JB(28,10,20,45), JB(29,10,20,48), JB(30,10,20,51),
  JB(31,10,20,55),
  JB(29,20,30,49), JB(30,20,30,52), JB(31,20,30,56),
  JB(8,0,9,255),  JB(18,10,19,17), JB(28,20,29,46),
  JB(7,0,8,255),  JB(17,10,18,15), JB(27,20,28,43),
  JB(6,0,7,255),  JB(16,10,17,13), JB(26,20,27,40),
  JB(5,0,6,255),  JB(15,10,16,11), JB(25,20,26,37),
  JB(4,0,5,255),  JB(14,10,15,9),  JB(24,20,25,34),
  JB(3,0,4,255),  JB(13,10,14,7),  JB(23,20,24,31),
  JB(2,0,3,255),  JB(12,10,13,5),  JB(22,20,23,28),
  JB(1,0,2,255),  JB(11,10,12,3),  JB(21,20,22,25), JB(31,30,32,57),
  JB(0,0,1,255),  JB(10,10,11,1),  JB(20,20,21,22), JB(30,30,31,53),
};

// ---------- batched weight transpose: f32 [R][C] -> bf16 [Npad][Rpad], 6 jobs
__global__ __launch_bounds__(256)
void transpose_all(const float* __restrict__ wq, const float* __restrict__ wk,
                   const float* __restrict__ wv, const float* __restrict__ wo,
                   const float* __restrict__ up, const float* __restrict__ dn,
                   char* __restrict__ ws) {
  const int bid = blockIdx.x;
  const float* src;
  bfbits* dst;
  int R, C, Rpad, Npad, gw, loc;
  if (bid < 4096) {
    R = C = Rpad = Npad = 1024; gw = 32;
    const int j = bid >> 10; loc = bid & 1023;
    src = (j == 0) ? wq : (j == 1) ? wk : (j == 2) ? wv : wo;
    dst = (j < 3) ? (bfbits*)(ws + OFF_WQKV) + (size_t)j * 1024 * 1024
                  : (bfbits*)(ws + OFF_WO);
  } else if (bid < 5760) {
    R = 1024; C = DFF_; Rpad = 1024; Npad = DFFP_; gw = 32; loc = bid - 4096;
    src = up; dst = (bfbits*)(ws + OFF_WUP);
  } else {
    R = DFF_; C = 1024; Rpad = DFFP_; Npad = 1024; gw = 52; loc = bid - 5760;
    src = dn; dst = (bfbits*)(ws + OFF_WDN);
  }
  const int kb = (loc % gw) * 32, nb = (loc / gw) * 32;
  __shared__ float tile[32][33];
  const int tx = threadIdx.x & 31, ty = threadIdx.x >> 5;
  for (int i = ty; i < 32; i += 8) {
    const int k = kb + i, n = nb + tx;
    tile[i][tx] = (k < R && n < C) ? src[(size_t)k * C + n] : 0.f;
  }
  __syncthreads();
  for (int i = ty; i < 32; i += 8) {
    const int n = nb + i, k = kb + tx;
    if (n < Npad && k < Rpad) dst[(size_t)n * Rpad + k] = f2bf(tile[tx][i]);
  }
}

// ---------- fused: bvec GEMV (blocks 0..31) + cb scalar dot (block 32)
__global__ __launch_bounds__(256)
void bvec_cb_kernel(const float* __restrict__ cfa, const float* __restrict__ bw,
                    const float* __restrict__ bb, const float* __restrict__ cbw,
                    float* __restrict__ bvec, float* __restrict__ cbv) {
  const int b = blockIdx.y;
  if (blockIdx.x == 32) {
    const int tid = threadIdx.x;
    float4 a = *(const float4*)(cfa + b * 1024 + tid * 4);
    float4 w = *(const float4*)(cbw + tid * 4);
    float s = a.x * w.x + a.y * w.y + a.z * w.z + a.w * w.w;
    #pragma unroll
    for (int o = 32; o > 0; o >>= 1) s += __shfl_xor(s, o);
    __shared__ float ls[4];
    if ((tid & 63) == 0) ls[tid >> 6] = s;
    __syncthreads();
    if (tid == 0) cbv[b] = ls[0] + ls[1] + ls[2] + ls[3];
    return;
  }
  const int dl = threadIdx.x & 31, cl = threadIdx.x >> 5;
  const int d = blockIdx.x * 32 + dl;
  const float* vb = cfa + b * 1024;
  float s = 0.f;
  #pragma unroll 4
  for (int c = cl; c < 1024; c += 8)
    s += vb[c] * bw[(size_t)c * 1024 + d];
  __shared__ float red[8][32];
  red[cl][dl] = s;
  __syncthreads();
  if (threadIdx.x < 32) {
    float t = 0.f;
    #pragma unroll
    for (int i = 0; i < 8; ++i) t += red[i][threadIdx.x];
    const int dd = blockIdx.x * 32 + threadIdx.x;
    bvec[b * 1024 + dd] = t + bb[dd];
  }
}

// ---------- GEMV: out[b][d] = tanh(vec[b] @ w[.][d] + bias[d])
__global__ __launch_bounds__(256)
void gemv_t(const float* __restrict__ v, const float* __restrict__ w,
            const float* __restrict__ bias, float* __restrict__ out) {
  const int b = blockIdx.y;
  const int dl = threadIdx.x & 31, cl = threadIdx.x >> 5;
  const int d = blockIdx.x * 32 + dl;
  const float* vb = v + b * 1024;
  float s = 0.f;
  #pragma unroll 4
  for (int c = cl; c < 1024; c += 8)
    s += vb[c] * w[(size_t)c * 1024 + d];
  __shared__ float red[8][32];
  red[cl][dl] = s;
  __syncthreads();
  if (threadIdx.x < 32) {
    float t = 0.f;
    #pragma unroll
    for (int i = 0; i < 8; ++i) t += red[i][threadIdx.x];
    const int dd = blockIdx.x * 32 + threadIdx.x;
    out[b * 1024 + dd] = tanhf(t + bias[dd]);
  }
}

__device__ __forceinline__ void blockreduce3(float& a, float& b, float& c) {
  #pragma unroll
  for (int o = 32; o > 0; o >>= 1) {
    a += __shfl_xor(a, o);
    b += __shfl_xor(b, o);
    c += __shfl_xor(c, o);
  }
  __shared__ float ls[3][4];
  const int lane = threadIdx.x & 63, w = threadIdx.x >> 6;
  if (lane == 0) { ls[0][w] = a; ls[1][w] = b; ls[2][w] = c; }
  __syncthreads();
  a = ls[0][0] + ls[0][1] + ls[0][2] + ls[0][3];
  b = ls[1][0] + ls[1][1] + ls[1][2] + ls[1][3];
  c = ls[2][0] + ls[2][1] + ls[2][2] + ls[2][3];
}

// ---------- fused: x1 = x + bvec ; gate ; LN(x1) -> h (bf16)
__global__ __launch_bounds__(256)
void ln1_kernel(const float* __restrict__ x, const float* __restrict__ bvec,
                const float* __restrict__ cbv, const float* __restrict__ gw,
                const float* __restrict__ gb, const float* __restrict__ nfg,
                const float* __restrict__ nfb, float* __restrict__ x1,
                bfbits* __restrict__ h, float* __restrict__ gate_ws,
                float* __restrict__ gate_out) {
  const int m = blockIdx.x, tid = threadIdx.x, b = m >> 11;
  const size_t ro = (size_t)m * D_ + tid * 4;
  float4 xv = *(const float4*)(x + ro);
  float4 bv = *(const float4*)(bvec + b * D_ + tid * 4);
  float4 v;
  v.x = xv.x + bv.x; v.y = xv.y + bv.y; v.z = xv.z + bv.z; v.w = xv.w + bv.w;
  float4 g4 = *(const float4*)(gw + tid * 4);
  float s  = v.x + v.y + v.z + v.w;
  float s2 = v.x*v.x + v.y*v.y + v.z*v.z + v.w*v.w;
  float dg = v.x*g4.x + v.y*g4.y + v.z*g4.z + v.w*g4.w;
  blockreduce3(s, s2, dg);
  const float mean = s * (1.0f/1024.0f);
  const float var  = s2 * (1.0f/1024.0f) - mean*mean;
  const float rstd = rsqrtf(var + 1e-5f);
  if (tid == 0) {
    const float logits = dg + gb[0] + cbv[b];
    const float prob = 1.0f / (1.0f + expf(-logits));
    const float hard = prob > 0.5f ? 1.0f : 0.0f;
    const float gv = (hard - prob) + prob;
    gate_ws[m] = gv; gate_out[m] = gv;
  }
  *(float4*)(x1 + ro) = v;
  float4 gg = *(const float4*)(nfg + tid * 4);
  float4 b2 = *(const float4*)(nfb + tid * 4);
  u16x4 hv;
  hv[0] = f2bf((v.x - mean) * rstd * gg.x + b2.x);
  hv[1] = f2bf((v.y - mean) * rstd * gg.y + b2.y);
  hv[2] = f2bf((v.z - mean) * rstd * gg.z + b2.z);
  hv[3] = f2bf((v.w - mean) * rstd * gg.w + b2.w);
  *(u16x4*)(h + ro) = hv;
}

__global__ __launch_bounds__(256)
void ln2_kernel(const float* __restrict__ x2, const float* __restrict__ gptr,
                const float* __restrict__ bptr, bfbits* __restrict__ h2) {
  const int m = blockIdx.x, tid = threadIdx.x;
  const size_t ro = (size_t)m * D_ + tid * 4;
  float4 v = *(const float4*)(x2 + ro);
  float s  = v.x + v.y + v.z + v.w;
  float s2 = v.x*v.x + v.y*v.y + v.z*v.z + v.w*v.w;
  float d0 = 0.f;
  blockreduce3(s, s2, d0);
  const float mean = s * (1.0f/1024.0f);
  const float var  = s2 * (1.0f/1024.0f) - mean*mean;
  const float rstd = rsqrtf(var + 1e-5f);
  float4 gg = *(const float4*)(gptr + tid * 4);
  float4 b2 = *(const float4*)(bptr + tid * 4);
  u16x4 hv;
  hv[0] = f2bf((v.x - mean) * rstd * gg.x + b2.x);
  hv[1] = f2bf((v.y - mean) * rstd * gg.y + b2.y);
  hv[2] = f2bf((v.z - mean) * rstd * gg.z + b2.z);
  hv[3] = f2bf((v.w - mean) * rstd * gg.w + b2.w);
  *(u16x4*)(h2 + ro) = hv;
}

// ---------- GEMM: C[M][N] = A[M][K](bf16) * Bt[N][K](bf16), double-buffered LDS,
// XOR-swizzled staging (source-side) so ds_read_b128 is ~conflict-free.
// EPI 0: QKV (rope+gate, Q*(1/8)*log2e; V -> V^T)  [128,32,128]
// EPI 1: WO (x2 = x1 + C*gate)                      [64,64,64]
// EPI 2: UP (gelu(C+up_b) -> bf16, ldc=1664)        [64,64,64]
// EPI 3: DN fused final (outx = x2+cmt*gate*(C+b))  [64,64,64]
template <int EPI, int BM, int BK, int BN>
__global__ void __launch_bounds__(256, 2)
gemm_bt(const bfbits* __restrict__ A, int lda,
        const bfbits* __restrict__ Bt, int ldb, int K,
        const float* __restrict__ p0, const float* __restrict__ p1,
        const float* __restrict__ p2,
        float* __restrict__ fo0, const float* __restrict__ fo1,
        bfbits* __restrict__ bo0, bfbits* __restrict__ bo1,
        bfbits* __restrict__ bo2) {
  constexpr int MI = BM / 32;               // m-fragments per wave
  constexpr int NJ = BN / 32;               // n-fragments per wave
  constexpr int RCH = BK / 8;               // 16B chunks per row
  constexpr int NK = BK / 32;               // 32-wide k sub-steps
  __shared__ bfbits Asl[2][BM * BK];
  __shared__ bfbits Bsl[2][BN * BK];
  const int tid = threadIdx.x;
  const int lane = tid & 63, wave = tid >> 6;
  const int g = lane >> 4, l15 = lane & 15;
  const int wr = wave >> 1, wc = wave & 1;
  const int m0 = blockIdx.y * BM, n0 = blockIdx.x * BN;

  auto stage = [&](int k0, int p) {
    #pragma unroll
    for (int i = 0; i < (BM * RCH) / 256; ++i) {
      const int c = i * 256 + tid;
      const int row = c / RCH;
      const int ko = ((c % RCH) ^ (row & (RCH - 1))) * 8;
      gload16(A + (size_t)(m0 + row) * lda + (k0 + ko),
              (char*)&Asl[p][0] + c * 16);
    }
    #pragma unroll
    for (int i = 0; i < (BN * RCH) / 256; ++i) {
      const int c = i * 256 + tid;
      const int row = c / RCH;
      const int ko = ((c % RCH) ^ (row & (RCH - 1))) * 8;
      gload16(Bt + (size_t)(n0 + row) * ldb + (k0 + ko),
              (char*)&Bsl[p][0] + c * 16);
    }
  };

  f32x4 acc[MI][NJ] = {};
  stage(0, 0);
  __syncthreads();

  int t = 0;
  for (int k0 = 0; k0 < K; k0 += BK, ++t) {
    const int p = t & 1;
    if (k0 + BK < K) stage(k0 + BK, p ^ 1);
    s16x8 af[NK][MI], bfr[NK][NJ];
    #pragma unroll
    for (int kk = 0; kk < NK; ++kk) {
      #pragma unroll
      for (int i = 0; i < MI; ++i) {
        const int row = wr * (MI * 16) + i * 16 + l15;
        af[kk][i] = *(const s16x8*)&Asl[p][row * BK + (((kk * 4 + g) ^ (row & (RCH - 1))) * 8)];
      }
      #pragma unroll
      for (int i = 0; i < NJ; ++i) {
        const int row = wc * (NJ * 16) + i * 16 + l15;
        bfr[kk][i] = *(const s16x8*)&Bsl[p][row * BK + (((kk * 4 + g) ^ (row & (RCH - 1))) * 8)];
      }
    }
    #pragma unroll
    for (int kk = 0; kk < NK; ++kk)
      #pragma unroll
      for (int i = 0; i < MI; ++i)
        #pragma unroll
        for (int j = 0; j < NJ; ++j)
          acc[i][j] = __builtin_amdgcn_mfma_f32_16x16x32_bf16(af[kk][i], bfr[kk][j], acc[i][j], 0, 0, 0);
    __syncthreads();
  }

  const int b = m0 >> 11;
  const int trow0 = (m0 & 2047) + wr * (MI * 16);

  if constexpr (EPI == 0) {
    const float* gate = p0;
    const float* phase = p1;
    const int ncol0 = n0 + wc * 64;
    const int section = ncol0 >> 10;          // 0=Q 1=K 2=V
    const int hh = (ncol0 & 1023) >> 6;
    if (section == 2) {
      bfbits* vt = bo2;
      const size_t vhead = (size_t)(b * H_ + hh) * DH_ * T_;
      #pragma unroll
      for (int mi = 0; mi < MI; ++mi) {
        const int tb = trow0 + mi * 16 + g * 4;
        #pragma unroll
        for (int ni = 0; ni < NJ; ++ni) {
          const int dh = ni * 16 + l15;
          unsigned* dst32 = (unsigned*)&vt[vhead + (size_t)dh * T_ + tb];
          dst32[0] = pkbf(acc[mi][ni][0], acc[mi][ni][1]);
          dst32[1] = pkbf(acc[mi][ni][2], acc[mi][ni][3]);
        }
      }
    } else {
      const float cc = cosf(phase[hh]);
      const float ssn = sinf(phase[hh]);
      // Q carries 1/sqrt(DH) and log2(e): scores land in exp2 domain.
      const float qs = (section == 0) ? 0.125f * 1.44269504088896341f : 1.0f;
      bfbits* dst = (section == 0) ? bo0 : bo1;
      const size_t head = (size_t)(b * H_ + hh) * T_ * DH_;
      #pragma unroll
      for (int mi = 0; mi < MI; ++mi) {
        const int tb = trow0 + mi * 16 + g * 4;
        float gv[4];
        #pragma unroll
        for (int r = 0; r < 4; ++r) gv[r] = gate[(size_t)b * T_ + tb + r] * qs;
        #pragma unroll
        for (int ni = 0; ni < 2; ++ni) {
          const int dh = ni * 16 + l15;
          #pragma unroll
          for (int r = 0; r < 4; ++r) {
            const float re = acc[mi][ni][r];
            const float im = acc[mi][ni + 2][r];
            const size_t idx = head + (size_t)(tb + r) * DH_ + dh;
            dst[idx]      = f2bf((re * cc - im * ssn) * gv[r]);
            dst[idx + 32] = f2bf((re * ssn + im * cc) * gv[r]);
          }
        }
      }
    }
  } else if constexpr (EPI == 1) {
    const float* gate = p0;
    const float* x1 = fo1;
    float* x2 = fo0;
    #pragma unroll
    for (int mi = 0; mi < MI; ++mi) {
      const int m = m0 + wr * (MI * 16) + mi * 16 + g * 4;
      float gv[4];
      #pragma unroll
      for (int r = 0; r < 4; ++r) gv[r] = gate[m + r];
      #pragma unroll
      for (int ni = 0; ni < NJ; ++ni) {
        const int n = n0 + wc * (NJ * 16) + ni * 16 + l15;
        #pragma unroll
        for (int r = 0; r < 4; ++r) {
          const size_t idx = (size_t)(m + r) * D_ + n;
          x2[idx] = x1[idx] + acc[mi][ni][r] * gv[r];
        }
      }
    }
  } else if constexpr (EPI == 2) {
    const float* upb = p0;
    bfbits* outm = bo0;
    #pragma unroll
    for (int mi = 0; mi < MI; ++mi) {
      const int m = m0 + wr * (MI * 16) + mi * 16 + g * 4;
      #pragma unroll
      for (int ni = 0; ni < NJ; ++ni) {
        const int n = n0 + wc * (NJ * 16) + ni * 16 + l15;
        const float bb = upb[n < DFF_ ? n : DFF_ - 1];
        #pragma unroll
        for (int r = 0; r < 4; ++r) {
          float v = acc[mi][ni][r] + bb;
          v = 0.5f * v * (1.0f + erff(v * 0.70710678118654752f));
          outm[(size_t)(m + r) * DFFP_ + n] = f2bf(v);
        }
      }
    }
  } else {
    const float* dnb = p0;
    const float* gate = p1;
    const float* cmt = p2;
    const float* x2 = fo1;
    float* outx = fo0;
    const float cb = cmt[b];
    #pragma unroll
    for (int mi = 0; mi < MI; ++mi) {
      const int m = m0 + wr * (MI * 16) + mi * 16 + g * 4;
      float kv[4];
      #pragma unroll
      for (int r = 0; r < 4; ++r) kv[r] = cb * gate[m + r];
      #pragma unroll
      for (int ni = 0; ni < NJ; ++ni) {
        const int n = n0 + wc * (NJ * 16) + ni * 16 + l15;
        const float bb = dnb[n];
        #pragma unroll
        for (int r = 0; r < 4; ++r) {
          const size_t idx = (size_t)(m + r) * D_ + n;
          outx[idx] = x2[idx] + kv[r] * (acc[mi][ni][r] + bb);
        }
      }
    }
  }
}

// ---------- flash attention v9c: uniform <=10-tile jobs + HW refill.
// 2176 blocks x 2 waves; wave owns 32 q-rows; KVBLK=64; single-buffer LDS.
// launch_bounds (128,3): 80+ VGPRs, NO spill (the (128,4) variant spilled:
// VGPR 64, +23MB scratch writes, 62us vs 41us). 6 blocks/CU + refill queue.
// Partial jobs store m,l (f32) + unnormalized O^T bf16 q-major; merged after.
__global__ void __launch_bounds__(128, 3)
attn_kernel(const bfbits* __restrict__ Qb, const bfbits* __restrict__ Kb,
            const bfbits* __restrict__ Vt, bfbits* __restrict__ AO,
            float* __restrict__ pm, float* __restrict__ pl,
            bfbits* __restrict__ pO) {
  __shared__ bfbits Kl[64 * 64];   // [k row][dh], chunk-swizzled
  __shared__ bfbits Vl[64 * 64];   // [dh row][k], chunk-swizzled
  const int pid = blockIdx.x;         // 0..2175
  const int bh = pid & 31;
  const unsigned job = JOBS2[pid >> 5];
  const int qt = job & 0xFF;
  const int t0 = (job >> 8) & 0xFF;
  const int t1 = (job >> 16) & 0xFF;
  const int js = job >> 24;           // 255 = full job
  const int qb0 = qt * 64;
  const int tid = threadIdx.x, lane = tid & 63, wq = tid >> 6;
  const int l31 = lane & 31, hi = lane >> 5;
  const int qw = qb0 + wq * 32;       // wave q base

  const bfbits* Qp = Qb + ((size_t)bh * T_ + qw) * DH_;
  const bfbits* Kp = Kb + (size_t)bh * T_ * DH_;
  const bfbits* Vp = Vt + (size_t)bh * DH_ * T_;

  // Q fragments (B-operand): lane l -> Q[qw + l31][mf*16 + hi*8 + e]
  s16x8 qf[4];
  #pragma unroll
  for (int mf = 0; mf < 4; ++mf)
    qf[mf] = *(const s16x8*)(Qp + l31 * DH_ + mf * 16 + hi * 8);

  f32x16 o0 = {}, o1 = {};            // O^T[dh][q], dh-halves 0..31 / 32..63
  float mrun = -INFINITY, lrun = 0.f;

  // staging: chunk c = i*128+tid; row=c>>3; src col chunk = (c&7)^(row&7)
  const bfbits* kg[4];
  const bfbits* vg[4];
  int cb_[4];
  #pragma unroll
  for (int i = 0; i < 4; ++i) {
    const int c = i * 128 + tid;
    const int row = c >> 3;
    const int sc = ((c & 7) ^ (row & 7)) * 8;
    kg[i] = Kp + row * DH_ + sc;
    vg[i] = Vp + (size_t)row * T_ + sc;
    cb_[i] = c * 16;
  }

  for (int t = t0; t < t1; ++t) {
    const int k0 = t << 6;
    #pragma unroll
    for (int i = 0; i < 4; ++i) {
      gload16(kg[i] + (size_t)k0 * DH_, (char*)&Kl[0] + cb_[i]);
      gload16(vg[i] + k0,               (char*)&Vl[0] + cb_[i]);
    }
    __syncthreads();                  // drains vmcnt -> tiles ready
    // ---- QK^T: S^T[64k][32q], two 32x32 halves ----
    f32x16 s0 = {}, s1 = {};
    __builtin_amdgcn_s_setprio(1);
    #pragma unroll
    for (int mf = 0; mf < 4; ++mf) {
      const int ch = ((mf * 2 + hi) ^ (l31 & 7)) * 8;
      const s16x8 ka  = *(const s16x8*)&Kl[l31 * 64 + ch];
      const s16x8 kb2 = *(const s16x8*)&Kl[(32 + l31) * 64 + ch];
      s0 = __builtin_amdgcn_mfma_f32_32x32x16_bf16(ka,  qf[mf], s0, 0, 0, 0);
      s1 = __builtin_amdgcn_mfma_f32_32x32x16_bf16(kb2, qf[mf], s1, 0, 0, 0);
    }
    __builtin_amdgcn_s_setprio(0);
    // ---- causal mask (only the diagonal tile t == qt) ----
    if (t == qt) {
      const int qd = wq * 32 + l31;       // q - k0
      #pragma unroll
      for (int r = 0; r < 16; ++r) {
        const int krow = (r & 3) + 8 * (r >> 2) + 4 * hi;
        if (krow > qd)      s0[r] = -1e9f;
        if (krow + 32 > qd) s1[r] = -1e9f;
      }
    }
    // ---- online softmax (exp2 domain), in-lane tree + 1 shfl ----
    float red[8];
    #pragma unroll
    for (int i = 0; i < 8; ++i)
      red[i] = fmaxf(fmaxf(s0[i], s0[i + 8]), fmaxf(s1[i], s1[i + 8]));
    #pragma unroll
    for (int i = 0; i < 4; ++i) red[i] = fmaxf(red[i], red[i + 4]);
    float mx = fmaxf(fmaxf(red[0], red[1]), fmaxf(red[2], red[3]));
    mx = fmaxf(mx, __shfl_xor(mx, 32));
    const bool need = __any(mx > mrun + 8.f) != 0;   // defer-max
    const float mnew = need ? fmaxf(mrun, mx) : mrun;
    s0 = s0 - mnew;
    s1 = s1 - mnew;
    #pragma unroll
    for (int i = 0; i < 16; ++i) { s0[i] = vexp2(s0[i]); s1[i] = vexp2(s1[i]); }
    float sr[8];
    #pragma unroll
    for (int i = 0; i < 8; ++i)
      sr[i] = (s0[i] + s0[i + 8]) + (s1[i] + s1[i + 8]);
    #pragma unroll
    for (int i = 0; i < 4; ++i) sr[i] += sr[i + 4];
    float sum = (sr[0] + sr[1]) + (sr[2] + sr[3]);
    sum += __shfl_xor(sum, 32);
    if (need) {
      const float alpha = vexp2(mrun - mnew);
      mrun = mnew;
      lrun = lrun * alpha + sum;
      o0 *= alpha;
      o1 *= alpha;
    } else {
      lrun += sum;
    }
    // ---- pack P subtiles + PV (O^T += V^T * P^T) ----
    #pragma unroll
    for (int mf = 0; mf < 4; ++mf) {
      const f32x16& s = (mf < 2) ? s0 : s1;
      const int r0 = (mf & 1) * 8;
      const unsigned A0 = pkbf(s[r0 + 0], s[r0 + 1]);
      const unsigned A1 = pkbf(s[r0 + 2], s[r0 + 3]);
      const unsigned B0 = pkbf(s[r0 + 4], s[r0 + 5]);
      const unsigned B1 = pkbf(s[r0 + 6], s[r0 + 7]);
      const unsigned x0 = (unsigned)__shfl_xor((int)(hi ? A0 : B0), 32);
      const unsigned x1 = (unsigned)__shfl_xor((int)(hi ? A1 : B1), 32);
      uint4 wv;
      wv.x = hi ? x0 : A0;
      wv.y = hi ? x1 : A1;
      wv.z = hi ? B0 : x0;
      wv.w = hi ? B1 : x1;
      const s16x8 pf = __builtin_bit_cast(s16x8, wv);
      const int ch = ((mf * 2 + hi) ^ (l31 & 7)) * 8;
      const s16x8 v0 = *(const s16x8*)&Vl[l31 * 64 + ch];
      const s16x8 v1 = *(const s16x8*)&Vl[(32 + l31) * 64 + ch];
      __builtin_amdgcn_s_setprio(1);
      o0 = __builtin_amdgcn_mfma_f32_32x32x16_bf16(v0, pf, o0, 0, 0, 0);
      o1 = __builtin_amdgcn_mfma_f32_32x32x16_bf16(v1, pf, o1, 0, 0, 0);
      __builtin_amdgcn_s_setprio(0);
    }
    __syncthreads();                  // all reads done before next overwrite
  }

  if (js == 255) {
    // ---- direct epilogue: reg r -> dh = (r&3)+8*(r>>2)+4*hi, col q = l31 ----
    const float inv = 1.0f / lrun;
    const int q = qw + l31;
    bfbits* dst = AO + ((size_t)(bh >> 4) * T_ + q) * D_ + (bh & 15) * DH_;
    #pragma unroll
    for (int rp = 0; rp < 8; ++rp) {
      const int dh = ((2 * rp) & 3) + 8 * (rp >> 1) + 4 * hi;
      *(unsigned*)(dst + dh)      = pkbf(o0[2 * rp] * inv, o0[2 * rp + 1] * inv);
      *(unsigned*)(dst + 32 + dh) = pkbf(o1[2 * rp] * inv, o1[2 * rp + 1] * inv);
    }
  } else {
    // ---- partial epilogue: m,l (f32); unnormalized O^T bf16, q-major row ----
    const int jid = bh * 58 + js;
    const int qloc = wq * 32 + l31;
    pm[jid * 64 + qloc] = mrun;
    pl[jid * 64 + qloc] = lrun;
    bfbits* po = pO + (size_t)jid * 4096 + qloc * 64;
    #pragma unroll
    for (int rp = 0; rp < 8; ++rp) {
      const int dh = ((2 * rp) & 3) + 8 * (rp >> 1) + 4 * hi;
      *(unsigned*)(po + dh)      = pkbf(o0[2 * rp], o0[2 * rp + 1]);
      *(unsigned*)(po + 32 + dh) = pkbf(o1[2 * rp], o1[2 * rp + 1]);
    }
  }
}

// ---------- merge split-K attention partials (qt 10..31, 2-4 parts) ----------
// 256 threads: thread t handles q=t>>2, dh0=(t&3)*16 -> 16 contiguous elements.
__global__ void __launch_bounds__(256)
attn_merge(const float* __restrict__ pm, const float* __restrict__ pl,
           const bfbits* __restrict__ pO, bfbits* __restrict__ AO) {
  __shared__ float evs[4][64];
  __shared__ float invs[64];
  const int u = blockIdx.x;             // 0..703
  const int qt = 10 + (u >> 5), bh = u & 31;
  const int tid = threadIdx.x;
  const int P = (qt + 10) / 10;         // ceil((qt+1)/10), 2..4
  const int pbase = (qt < 20) ? (qt - 10) * 2
                  : (qt < 30) ? 20 + (qt - 20) * 3
                              : 50 + (qt - 30) * 4;
  const int jb = bh * 58 + pbase;
  if (tid < 64) {
    const int q = tid;
    float mv[4];
    float m = -INFINITY;
    for (int p = 0; p < P; ++p) {
      mv[p] = pm[(jb + p) * 64 + q];
      m = fmaxf(m, mv[p]);
    }
    float l = 0.f;
    for (int p = 0; p < P; ++p) {
      const float e = vexp2(mv[p] - m);
      evs[p][q] = e;
      l += pl[(jb + p) * 64 + q] * e;
    }
    invs[q] = 1.0f / l;
  }
  __syncthreads();
  const int q = tid >> 2, dh0 = (tid & 3) * 16;
  float acc[16] = {};
  for (int p = 0; p < P; ++p) {
    const float e = evs[p][q];
    const bfbits* src = pO + (size_t)(jb + p) * 4096 + q * 64 + dh0;
    const u16x8 a = *(const u16x8*)src;
    const u16x8 b2 = *(const u16x8*)(src + 8);
    #pragma unroll
    for (int i = 0; i < 8; ++i) {
      acc[i]     += bf2f(a[i]) * e;
      acc[8 + i] += bf2f(b2[i]) * e;
    }
  }
  const float inv = invs[q];
  uint4 w0, w1;
  w0.x = pkbf(acc[0] * inv,  acc[1] * inv);
  w0.y = pkbf(acc[2] * inv,  acc[3] * inv);
  w0.z = pkbf(acc[4] * inv,  acc[5] * inv);
  w0.w = pkbf(acc[6] * inv,  acc[7] * inv);
  w1.x = pkbf(acc[8] * inv,  acc[9] * inv);
  w1.y = pkbf(acc[10] * inv, acc[11] * inv);
  w1.z = pkbf(acc[12] * inv, acc[13] * inv);
  w1.w = pkbf(acc[14] * inv, acc[15] * inv);
  const int b = bh >> 4, hh = bh & 15;
  bfbits* dst = AO + ((size_t)b * T_ + qt * 64 + q) * D_ + hh * DH_ + dh0;
  *(uint4*)dst = w0;
  *(uint4*)(dst + 8) = w1;
}

// ---------- pooling / commit ----------
__global__ __launch_bounds__(256)
void pool_part(const float* __restrict__ x2, float* __restrict__ part) {
  const int s = blockIdx.x, b = blockIdx.y, tid = threadIdx.x;
  const float* base = x2 + ((size_t)b * T_ + s * 32) * D_ + tid * 4;
  float ax = 0, ay = 0, az = 0, aw = 0;
  #pragma unroll 4
  for (int t = 0; t < 32; ++t) {
    float4 v = *(const float4*)(base + (size_t)t * D_);
    ax += v.x; ay += v.y; az += v.z; aw += v.w;
  }
  float4 ov; ov.x = ax; ov.y = ay; ov.z = az; ov.w = aw;
  *(float4*)(part + (size_t)(b * 64 + s) * D_ + tid * 4) = ov;
}

// pool_fin + commit fused: block b computes pool row AND commit[b]
__global__ __launch_bounds__(256)
void pool_fin_commit(const float* __restrict__ part, const float* __restrict__ cw,
                     const float* __restrict__ cb0, float* __restrict__ pool,
                     float* __restrict__ cmt, float* __restrict__ out_cmt) {
  const int b = blockIdx.x, tid = threadIdx.x;
  const int d0 = tid * 4;
  float ax = 0, ay = 0, az = 0, aw = 0;
  #pragma unroll 8
  for (int i = 0; i < 64; ++i) {
    float4 v = *(const float4*)(part + (size_t)(b * 64 + i) * D_ + d0);
    ax += v.x; ay += v.y; az += v.z; aw += v.w;
  }
  ax *= (1.0f / 2048.0f); ay *= (1.0f / 2048.0f);
  az *= (1.0f / 2048.0f); aw *= (1.0f / 2048.0f);
  float4 ov; ov.x = ax; ov.y = ay; ov.z = az; ov.w = aw;
  *(float4*)(pool + b * 1024 + d0) = ov;
  float4 w = *(const float4*)(cw + d0);
  float s = ax * w.x + ay * w.y + az * w.z + aw * w.w;
  #pragma unroll
  for (int o = 32; o > 0; o >>= 1) s += __shfl_xor(s, o);
  __shared__ float ls[4];
  if ((tid & 63) == 0) ls[tid >> 6] = s;
  __syncthreads();
  if (tid == 0) {
    const float t = ls[0] + ls[1] + ls[2] + ls[3] + cb0[0];
    const float v = 1.0f / (1.0f + expf(-t));
    cmt[b] = v; out_cmt[b] = v;
  }
}

// ---------------- host launcher ----------------
extern "C" void kernel_launch(void* const* d_in, const int* in_sizes, int n_in,
                              void* d_out, int out_size, void* d_ws, size_t ws_size,
                              hipStream_t stream) {
  (void)in_sizes; (void)n_in; (void)out_size; (void)ws_size;
  const float* x       = (const float*)d_in[0];
  const float* cfa     = (const float*)d_in[1];
  const float* gate_w  = (const float*)d_in[3];
  const float* gate_b  = (const float*)d_in[4];
  const float* cb_w    = (const float*)d_in[5];
  const float* nf_g    = (const float*)d_in[6];
  const float* nf_b    = (const float*)d_in[7];
  const float* wq      = (const float*)d_in[8];
  const float* wk      = (const float*)d_in[9];
  const float* wv      = (const float*)d_in[10];
  const float* wo      = (const float*)d_in[11];
  const float* phase   = (const float*)d_in[12];
  const float* nb_g    = (const float*)d_in[13];
  const float* nb_b    = (const float*)d_in[14];
  const float* up_w    = (const float*)d_in[15];
  const float* up_b    = (const float*)d_in[16];
  const float* dn_w    = (const float*)d_in[17];
  const float* dn_b    = (const float*)d_in[18];
  const float* cmt_w   = (const float*)d_in[19];
  const float* cmt_b   = (const float*)d_in[20];
  const float* cproj_w = (const float*)d_in[21];
  const float* cproj_b = (const float*)d_in[22];
  const float* bcast_w = (const float*)d_in[23];
  const float* bcast_b = (const float*)d_in[24];

  char* ws = (char*)d_ws;
  float*  x1     = (float*)(ws + OFF_X1);
  bfbits* h      = (bfbits*)(ws + OFF_H);
  bfbits* h2     = (bfbits*)(ws + OFF_H);     // alias: h dead after QKV
  bfbits* qb     = (bfbits*)(ws + OFF_Q);
  bfbits* kb     = (bfbits*)(ws + OFF_K);
  bfbits* vt     = (bfbits*)(ws + OFF_VT);
  bfbits* ffmid  = (bfbits*)(ws + OFF_Q);     // alias: Q/K dead after attention
  bfbits* ao     = (bfbits*)(ws + OFF_AO);
  float*  x2     = (float*)(ws + OFF_X2);
  bfbits* pO     = (bfbits*)(ws + OFF_X2);    // alias: x2 written after merge
  bfbits* wqkv_t = (bfbits*)(ws + OFF_WQKV);
  bfbits* wo_t   = (bfbits*)(ws + OFF_WO);
  bfbits* wup_t  = (bfbits*)(ws + OFF_WUP);
  bfbits* wdn_t  = (bfbits*)(ws + OFF_WDN);
  float*  bvec   = (float*)(ws + OFF_BVEC);
  float*  cbv    = (float*)(ws + OFF_CBV);
  float*  gate   = (float*)(ws + OFF_GATE);
  float*  part   = (float*)(ws + OFF_PART);
  float*  pool   = (float*)(ws + OFF_POOL);
  float*  cmt    = (float*)(ws + OFF_CMT);
  float*  pm     = (float*)(ws + OFF_PM);
  float*  pl     = (float*)(ws + OFF_PL);

  float* outx   = (float*)d_out;
  float* outc   = outx + NELEM_X;          // center [B][DC]
  float* outg   = outc + B_ * DC_;         // gate [B][T]
  float* outcmt = outg + B_ * T_;          // commit [B]

  // weight prep (B^T bf16), all 6 in one launch
  transpose_all<<<7424, 256, 0, stream>>>(wq, wk, wv, wo, up_w, dn_w, ws);

  bvec_cb_kernel<<<dim3(33, B_), 256, 0, stream>>>(cfa, bcast_w, bcast_b, cb_w,
                                                   bvec, cbv);

  ln1_kernel<<<MTOT, 256, 0, stream>>>(x, bvec, cbv, gate_w, gate_b, nf_g, nf_b,
                                       x1, h, gate, outg);

  gemm_bt<0, 128, 32, 128><<<dim3(24, 32), 256, 0, stream>>>(
      h, 1024, wqkv_t, 1024, 1024, gate, phase, nullptr,
      nullptr, nullptr, qb, kb, vt);

  attn_kernel<<<2176, 128, 0, stream>>>(qb, kb, vt, ao, pm, pl, pO);
  attn_merge<<<704, 256, 0, stream>>>(pm, pl, pO, ao);

  gemm_bt<1, 64, 64, 64><<<dim3(16, 64), 256, 0, stream>>>(
      ao, 1024, wo_t, 1024, 1024, gate, nullptr, nullptr,
      x2, x1, nullptr, nullptr, nullptr);

  ln2_kernel<<<MTOT, 256, 0, stream>>>(x2, nb_g, nb_b, h2);

  // pooled stats only need x2 -> run before FF so DN can fuse the final add
  pool_part<<<dim3(64, B_), 256, 0, stream>>>(x2, part);
  pool_fin_commit<<<B_, 256, 0, stream>>>(part, cmt_w, cmt_b, pool, cmt, outcmt);
  gemv_t<<<dim3(32, B_), 256, 0, stream>>>(pool, cproj_w, cproj_b, outc);

  gemm_bt<2, 64, 64, 64><<<dim3(26, 64), 256, 0, stream>>>(
      h2, 1024, wup_t, 1024, 1024, up_b, nullptr, nullptr,
      nullptr, nullptr, ffmid, nullptr, nullptr);

  gemm_bt<3, 64, 64, 64><<<dim3(16, 64), 256, 0, stream>>>(
      ffmid, DFFP_, wdn_t, DFFP_, DFFP_, dn_b, gate, cmt,
      outx, x2, nullptr, nullptr, nullptr);
}